// Round 4
// baseline (728.662 us; speedup 1.0000x reference)
//
#include <hip/hip_runtime.h>
#include <hip/hip_cooperative_groups.h>
#include <cstddef>
#include <cstdint>

namespace cg = cooperative_groups;

#define N_NODES 50000
#define N_EDGES 600000
#define M_TILES 3125     // 50000 / 16 exactly
#define GEMM_UNITS 782   // ceil(3125/4)
#define GEMM_BLKS 782
#define NBUCK 196        // ceil(50000/256) coarse buckets (dst>>8)
#define BUCK_CAP 4096    // bucket total ~3072 +- 55
#define ROUTE_EDGES 2048 // edges routed per route unit
#define ROUTE_UNITS 293  // ceil(600000/2048)
#define ROUTE_BLKS 293

typedef short bf16x8 __attribute__((ext_vector_type(8)));
typedef float f32x4 __attribute__((ext_vector_type(4)));

// ---------------- bf16 helpers ----------------

__device__ __forceinline__ unsigned short f32_to_bf16(float x) {
  unsigned u = __float_as_uint(x);
  u += 0x7FFFu + ((u >> 16) & 1u);  // round-to-nearest-even
  return (unsigned short)(u >> 16);
}
__device__ __forceinline__ float bf16_to_f32(unsigned short h) {
  return __uint_as_float((unsigned)h << 16);
}
__device__ __forceinline__ float bf16_lo(unsigned g) {
  return __uint_as_float(g << 16);
}
__device__ __forceinline__ float bf16_hi(unsigned g) {
  return __uint_as_float(g & 0xFFFF0000u);
}

// Split 8 contiguous fp32 into bf16 hi + bf16 lo fragments (in-register).
__device__ __forceinline__ void split8(const float* __restrict__ p, bf16x8& hi,
                                       bf16x8& lo) {
  const float4 v0 = *(const float4*)p;
  const float4 v1 = *(const float4*)(p + 4);
  float v[8] = {v0.x, v0.y, v0.z, v0.w, v1.x, v1.y, v1.z, v1.w};
#pragma unroll
  for (int i = 0; i < 8; i++) {
    const unsigned short h = f32_to_bf16(v[i]);
    hi[i] = (short)h;
    lo[i] = (short)f32_to_bf16(v[i] - bf16_to_f32(h));
  }
}

// ---------------- MFMA GEMM body: H(bf16) = X[N,128](fp32) @ W[128,COUT] ---
template <int COUT>
__device__ __forceinline__ void gemm_body(const int wtile, const int lane,
                                          const float* __restrict__ X,
                                          const unsigned short* __restrict__ Wph,
                                          const unsigned short* __restrict__ Wpl,
                                          unsigned short* __restrict__ Hs) {
  constexpr int CT = COUT / 16;
  const int m = lane & 15;
  const int q = lane >> 4;

  f32x4 acc[CT];
#pragma unroll
  for (int ct = 0; ct < CT; ct++) acc[ct] = {0.f, 0.f, 0.f, 0.f};

  const float* xp = X + (size_t)(wtile * 16 + m) * 128 + q * 8;

#pragma unroll
  for (int ks = 0; ks < 4; ks++) {
    bf16x8 ah, al;
    split8(xp + ks * 32, ah, al);
#pragma unroll
    for (int ct = 0; ct < CT; ct++) {
      const size_t bo = ((size_t)(ct * 4 + ks) * 64 + lane) * 8;
      const bf16x8 bh = *(const bf16x8*)(Wph + bo);
      const bf16x8 bl = *(const bf16x8*)(Wpl + bo);
      acc[ct] = __builtin_amdgcn_mfma_f32_16x16x32_bf16(ah, bh, acc[ct], 0, 0, 0);
      acc[ct] = __builtin_amdgcn_mfma_f32_16x16x32_bf16(al, bh, acc[ct], 0, 0, 0);
      acc[ct] = __builtin_amdgcn_mfma_f32_16x16x32_bf16(ah, bl, acc[ct], 0, 0, 0);
    }
  }
  // C/D layout: col = lane&15 (=m), row = q*4 + r
#pragma unroll
  for (int ct = 0; ct < CT; ct++) {
#pragma unroll
    for (int r = 0; r < 4; r++) {
      const int orow = wtile * 16 + q * 4 + r;
      Hs[(size_t)orow * COUT + ct * 16 + m] = f32_to_bf16(acc[ct][r]);
    }
  }
}

// ---------------- W-pack body (shared by mega P0 and fallback) ----------
__device__ __forceinline__ void wpack_body(const int i,
                                           const float* __restrict__ W1,
                                           const float* __restrict__ W2,
                                           unsigned short* __restrict__ w1h,
                                           unsigned short* __restrict__ w1l,
                                           unsigned short* __restrict__ w2h,
                                           unsigned short* __restrict__ w2l) {
  // Wp[((ct*4+ks)*64+lane)*8+j] = W[(ks*32+(lane>>4)*8+j)*COUT + ct*16+(lane&15)]
  const float* W;
  unsigned short *wh, *wl;
  int o, cout;
  if (i < 16384) {
    W = W1; wh = w1h; wl = w1l; o = i; cout = 128;
  } else {
    W = W2; wh = w2h; wl = w2l; o = i - 16384; cout = 64;
  }
  const int j = o & 7;
  const int ln = (o >> 3) & 63;
  const int t = o >> 9;  // ct*4 + ks
  const int ks = t & 3;
  const int ct = t >> 2;
  const int k = ks * 32 + (ln >> 4) * 8 + j;
  const int n = ct * 16 + (ln & 15);
  const float v = W[k * cout + n];
  const unsigned short h = f32_to_bf16(v);
  wh[o] = h;
  wl[o] = f32_to_bf16(v - bf16_to_f32(h));
}

// ================== single cooperative kernel: 5 phases ==================
// P0: W-pack (96 units) + cursor zero.
// P1: edge routing (293 units) || GEMM1 (782 units), grid-stride.
// P2: per-bucket counting sort (196 units) — no LDS staging; routed[] is
//     read twice from L2 instead (drops static LDS 18.4K -> 8.4K so 4
//     blocks/CU fit: 16 waves/CU vs round-3's 8).
// P3: layer-1 aggregation + GEMM2 (3125 units, grid-stride).
// P4: layer-2 aggregation (3125 units, grid-stride).
// All loops stride by gridDim.x; grid size chosen at launch from the
// occupancy query (round-2's cooperative-launch rejection can't recur).
__global__ __launch_bounds__(256, 4) void k_mega(
    const float* __restrict__ X, const int* __restrict__ src,
    const int* __restrict__ dst, const float* __restrict__ W1,
    const float* __restrict__ b1, const float* __restrict__ W2,
    const float* __restrict__ b2, int* __restrict__ cursor,
    unsigned* __restrict__ routed, int* __restrict__ sorted_src,
    int* __restrict__ counts, int* __restrict__ start,
    unsigned short* __restrict__ w1h, unsigned short* __restrict__ w1l,
    unsigned short* __restrict__ w2h, unsigned short* __restrict__ w2l,
    unsigned short* __restrict__ h1b, unsigned short* __restrict__ h2b,
    float* __restrict__ out) {
  __shared__ __align__(16) unsigned char smem[16 * 132 * 4];  // 8448 B union
  cg::grid_group grid = cg::this_grid();
  const int tid = threadIdx.x;
  const int bid = blockIdx.x;
  const int nblk = gridDim.x;
  const int lane = tid & 63;
  const int wave = tid >> 6;

  // ---------------- P0: W-pack + cursor zero ----------------
  if (bid < 96) {
    wpack_body(bid * 256 + tid, W1, W2, w1h, w1l, w2h, w2l);
  } else if (bid == 96) {
    if (tid < NBUCK) cursor[tid] = 0;
  }
  __threadfence();
  grid.sync();
  __threadfence();

  // ---------------- P1: routing || GEMM1 ----------------
  for (int u = bid; u < ROUTE_UNITS + GEMM_UNITS; u += nblk) {
    if (u < ROUTE_UNITS) {
      int* hist = (int*)smem;
      int* lcur = hist + NBUCK;
      for (int t = tid; t < NBUCK; t += 256) hist[t] = 0;
      __syncthreads();
      unsigned packed[8];
      bool cvalid[2];
      const int base = u * ROUTE_EDGES;
#pragma unroll
      for (int c = 0; c < 2; c++) {
        const int i4 = base + c * 1024 + tid * 4;  // always mult of 4
        cvalid[c] = (i4 < N_EDGES);
        if (cvalid[c]) {
          const int4 d4 = *(const int4*)(dst + i4);
          const int4 s4 = *(const int4*)(src + i4);
          packed[c * 4 + 0] = ((unsigned)d4.x << 16) | (unsigned)s4.x;
          packed[c * 4 + 1] = ((unsigned)d4.y << 16) | (unsigned)s4.y;
          packed[c * 4 + 2] = ((unsigned)d4.z << 16) | (unsigned)s4.z;
          packed[c * 4 + 3] = ((unsigned)d4.w << 16) | (unsigned)s4.w;
#pragma unroll
          for (int j = 0; j < 4; j++)
            atomicAdd(&hist[packed[c * 4 + j] >> 24], 1);  // LDS atomic
        }
      }
      __syncthreads();
      // one device atomic per bucket: claim contiguous range in the region
      for (int t = tid; t < NBUCK; t += 256)
        lcur[t] = t * BUCK_CAP + atomicAdd(&cursor[t], hist[t]);
      __syncthreads();
#pragma unroll
      for (int c = 0; c < 2; c++) {
        if (cvalid[c]) {
#pragma unroll
          for (int j = 0; j < 4; j++) {
            const unsigned pk = packed[c * 4 + j];
            const int slot = atomicAdd(&lcur[pk >> 24], 1);  // LDS atomic
            routed[slot] = pk;
          }
        }
      }
      __syncthreads();  // hist/lcur reuse guard across loop iterations
    } else {
      const int wtile = (u - ROUTE_UNITS) * 4 + wave;
      if (wtile < M_TILES) gemm_body<128>(wtile, lane, X, w1h, w1l, h1b);
    }
  }
  __threadfence();
  grid.sync();
  __threadfence();

  // ---------------- P2: per-bucket counting sort (no LDS staging) -------
  for (int b = bid; b < NBUCK; b += nblk) {
    int* h2 = (int*)smem;
    int* c2 = h2 + 256;
    const int n = cursor[b];  // count-based
    const unsigned* __restrict__ rb = routed + b * BUCK_CAP;
    h2[tid] = 0;
    __syncthreads();
    for (int i = tid; i < n; i += 256)
      atomicAdd(&h2[(rb[i] >> 16) & 255], 1);
    __syncthreads();
    const int own = h2[tid];
    for (int s = 1; s < 256; s <<= 1) {
      const int t = (tid >= s) ? h2[tid - s] : 0;
      __syncthreads();
      h2[tid] += t;
      __syncthreads();
    }
    const int pfx = h2[tid] - own;  // exclusive prefix
    c2[tid] = pfx;
    const int d = b * 256 + tid;
    if (d < N_NODES) {
      counts[d] = own;
      start[d] = b * BUCK_CAP + pfx;
    }
    __syncthreads();
    for (int i = tid; i < n; i += 256) {
      const unsigned pk = rb[i];  // second read: L2-hot
      const int r = atomicAdd(&c2[(pk >> 16) & 255], 1);  // LDS atomic
      sorted_src[b * BUCK_CAP + r] = (int)(pk & 0xFFFFu);
    }
    __syncthreads();  // h2/c2 reuse guard
  }
  __threadfence();
  grid.sync();
  __threadfence();

  // ---------------- P3: layer-1 aggregation + GEMM2 ----------------
  // Half-wave (32 lanes x uint2 = full 256 B row) per node; each load
  // gathers edge rows for TWO nodes. Accumulation order identical to the
  // per-edge version -> bitwise-identical results.
  {
    float(*a1s)[132] = (float(*)[132])smem;  // 16 x 132 fp32, +4 pad
    const int h = lane >> 5;  // half id: which node of the pair
    const int c = lane & 31;  // uint2 column within the 256 B row
    const uint2* __restrict__ Hb2 = (const uint2*)h1b;
    const float4 bb = ((const float4*)b1)[c];

    for (int u = bid; u < M_TILES; u += nblk) {
      const int vbase = u * 16 + wave * 4;
#pragma unroll
      for (int p = 0; p < 2; p++) {
        const int v = vbase + 2 * p + h;
        const int deg = counts[v];
        const int e0 = start[v];
        const float dv = rsqrtf((float)deg + 1.0f);
        const uint2 gs = Hb2[(size_t)v * 32 + c];
        int si = 0;
        float wi = 0.f;
        if (c < deg) {
          si = sorted_src[e0 + c];
          wi = rsqrtf((float)counts[si] + 1.0f) * dv;
        }
        const int dA = __shfl(deg, 0);
        const int dB = __shfl(deg, 32);
        const int mm = max(dA, dB);
        const int m = min(mm, 32);
        const float dv2 = dv * dv;
        float a0 = bf16_lo(gs.x) * dv2;
        float a1 = bf16_hi(gs.x) * dv2;
        float a2 = bf16_lo(gs.y) * dv2;
        float a3 = bf16_hi(gs.y) * dv2;

        for (int j = 0; j < m; j += 8) {
          int s[8];
          float w[8];
          uint2 g[8];
#pragma unroll
          for (int t = 0; t < 8; t++) {
            s[t] = __shfl(si, (lane & 32) | (j + t));
            w[t] = __shfl(wi, (lane & 32) | (j + t));
          }
#pragma unroll
          for (int t = 0; t < 8; t++) g[t] = Hb2[(size_t)s[t] * 32 + c];
#pragma unroll
          for (int t = 0; t < 8; t++) {
            a0 += bf16_lo(g[t].x) * w[t];
            a1 += bf16_hi(g[t].x) * w[t];
            a2 += bf16_lo(g[t].y) * w[t];
            a3 += bf16_hi(g[t].y) * w[t];
          }
        }
        // rare tail: deg > 32 (max in-degree ~35 for this input)
        for (int base = 32; base < mm; base += 32) {
          int sit = 0;
          float wit = 0.f;
          if (base + c < deg) {
            sit = sorted_src[e0 + base + c];
            wit = rsqrtf((float)counts[sit] + 1.0f) * dv;
          }
          const int lim = min(32, mm - base);
          for (int k = 0; k < lim; k++) {
            const int s = __shfl(sit, (lane & 32) | k);
            const float w = __shfl(wit, (lane & 32) | k);
            const uint2 g = Hb2[(size_t)s * 32 + c];
            a0 += bf16_lo(g.x) * w;
            a1 += bf16_hi(g.x) * w;
            a2 += bf16_lo(g.y) * w;
            a3 += bf16_hi(g.y) * w;
          }
        }
        float4 r;
        r.x = fmaxf(a0 + bb.x, 0.f);
        r.y = fmaxf(a1 + bb.y, 0.f);
        r.z = fmaxf(a2 + bb.z, 0.f);
        r.w = fmaxf(a3 + bb.w, 0.f);
        *(float4*)&a1s[wave * 4 + 2 * p + h][c * 4] = r;  // 528 B rows
      }
      __syncthreads();

      // GEMM2: each wave computes one 16x16 column tile of h2 = a1 @ W2
      const int ct = wave;
      const int m2 = lane & 15;
      const int q = lane >> 4;
      f32x4 acc = {0.f, 0.f, 0.f, 0.f};
#pragma unroll
      for (int ks = 0; ks < 4; ks++) {
        bf16x8 ah, al;
        split8(&a1s[m2][ks * 32 + q * 8], ah, al);
        const size_t bo = ((size_t)(ct * 4 + ks) * 64 + lane) * 8;
        const bf16x8 bh = *(const bf16x8*)(w2h + bo);
        const bf16x8 bl = *(const bf16x8*)(w2l + bo);
        acc = __builtin_amdgcn_mfma_f32_16x16x32_bf16(ah, bh, acc, 0, 0, 0);
        acc = __builtin_amdgcn_mfma_f32_16x16x32_bf16(al, bh, acc, 0, 0, 0);
        acc = __builtin_amdgcn_mfma_f32_16x16x32_bf16(ah, bl, acc, 0, 0, 0);
      }
#pragma unroll
      for (int r = 0; r < 4; r++) {
        const int orow = u * 16 + q * 4 + r;
        h2b[(size_t)orow * 64 + ct * 16 + m2] = f32_to_bf16(acc[r]);
      }
      __syncthreads();  // a1s reuse guard before next unit
    }
  }
  __threadfence();
  grid.sync();
  __threadfence();

  // ---------------- P4: layer-2 aggregation (COUT=64, no relu) ----------
  // Quarter-wave (16 lanes x uint2 = full 128 B row) per node; one load
  // gathers edge rows for FOUR nodes. Accumulation order identical.
  {
    const int qq = lane >> 4;  // quarter id: which node
    const int c = lane & 15;   // uint2 column within the 128 B row
    const uint2* __restrict__ Hb2 = (const uint2*)h2b;
    const float4 bb = ((const float4*)b2)[c];

    for (int u = bid; u < M_TILES; u += nblk) {
      const int v = u * 16 + wave * 4 + qq;
      const int deg = counts[v];
      const int e0 = start[v];
      const float dv = rsqrtf((float)deg + 1.0f);
      const uint2 gs = Hb2[(size_t)v * 16 + c];
      int si0 = 0, si1 = 0;
      float wi0 = 0.f, wi1 = 0.f;
      if (c < deg) {
        si0 = sorted_src[e0 + c];
        wi0 = rsqrtf((float)counts[si0] + 1.0f) * dv;
      }
      if (c + 16 < deg) {
        si1 = sorted_src[e0 + c + 16];
        wi1 = rsqrtf((float)counts[si1] + 1.0f) * dv;
      }
      const int d0 = __shfl(deg, 0);
      const int d1 = __shfl(deg, 16);
      const int d2 = __shfl(deg, 32);
      const int d3 = __shfl(deg, 48);
      const int mm = max(max(d0, d1), max(d2, d3));
      const int m = min(mm, 32);
      const float dv2 = dv * dv;
      float a0 = bf16_lo(gs.x) * dv2;
      float a1 = bf16_hi(gs.x) * dv2;
      float a2 = bf16_lo(gs.y) * dv2;
      float a3 = bf16_hi(gs.y) * dv2;

#pragma unroll
      for (int jb = 0; jb < 4; jb++) {
        if (jb * 8 < m) {
          int s[8];
          float w[8];
          uint2 g[8];
#pragma unroll
          for (int t = 0; t < 8; t++) {
            const int e = jb * 8 + t;  // 0..31
            const int srcl = (lane & 48) | (e & 15);
            s[t] = __shfl((jb < 2) ? si0 : si1, srcl);
            w[t] = __shfl((jb < 2) ? wi0 : wi1, srcl);
          }
#pragma unroll
          for (int t = 0; t < 8; t++) g[t] = Hb2[(size_t)s[t] * 16 + c];
#pragma unroll
          for (int t = 0; t < 8; t++) {
            a0 += bf16_lo(g[t].x) * w[t];
            a1 += bf16_hi(g[t].x) * w[t];
            a2 += bf16_lo(g[t].y) * w[t];
            a3 += bf16_hi(g[t].y) * w[t];
          }
        }
      }
      // rare tail: deg > 32
      for (int base = 32; base < mm; base += 16) {
        int sit = 0;
        float wit = 0.f;
        if (base + c < deg) {
          sit = sorted_src[e0 + base + c];
          wit = rsqrtf((float)counts[sit] + 1.0f) * dv;
        }
        const int lim = min(16, mm - base);
        for (int k = 0; k < lim; k++) {
          const int s = __shfl(sit, (lane & 48) | k);
          const float w = __shfl(wit, (lane & 48) | k);
          const uint2 g = Hb2[(size_t)s * 16 + c];
          a0 += bf16_lo(g.x) * w;
          a1 += bf16_hi(g.x) * w;
          a2 += bf16_lo(g.y) * w;
          a3 += bf16_hi(g.y) * w;
        }
      }
      float4 r;
      r.x = a0 + bb.x;
      r.y = a1 + bb.y;
      r.z = a2 + bb.z;
      r.w = a3 + bb.w;
      ((float4*)out)[(size_t)v * 16 + c] = r;
    }
  }
}

// ================== fallback pipeline (round-1 verified, 152.9 us) =======

__global__ __launch_bounds__(256) void k_prep_route(
    const float* __restrict__ W1, const float* __restrict__ W2,
    unsigned short* __restrict__ w1h, unsigned short* __restrict__ w1l,
    unsigned short* __restrict__ w2h, unsigned short* __restrict__ w2l,
    const int* __restrict__ src, const int* __restrict__ dst,
    int* __restrict__ cursor, unsigned* __restrict__ routed) {
  __shared__ int hist[NBUCK];
  __shared__ int lcur[NBUCK];
  const int tid = threadIdx.x;
  if (blockIdx.x < 96) {
    wpack_body(blockIdx.x * 256 + tid, W1, W2, w1h, w1l, w2h, w2l);
  } else {
    const int rb = blockIdx.x - 96;
    for (int t = tid; t < NBUCK; t += 256) hist[t] = 0;
    __syncthreads();
    unsigned packed[8];
    bool cvalid[2];
    const int base = rb * ROUTE_EDGES;
#pragma unroll
    for (int c = 0; c < 2; c++) {
      const int i4 = base + c * 1024 + tid * 4;
      cvalid[c] = (i4 < N_EDGES);
      if (cvalid[c]) {
        const int4 d4 = *(const int4*)(dst + i4);
        const int4 s4 = *(const int4*)(src + i4);
        packed[c * 4 + 0] = ((unsigned)d4.x << 16) | (unsigned)s4.x;
        packed[c * 4 + 1] = ((unsigned)d4.y << 16) | (unsigned)s4.y;
        packed[c * 4 + 2] = ((unsigned)d4.z << 16) | (unsigned)s4.z;
        packed[c * 4 + 3] = ((unsigned)d4.w << 16) | (unsigned)s4.w;
#pragma unroll
        for (int j = 0; j < 4; j++)
          atomicAdd(&hist[packed[c * 4 + j] >> 24], 1);
      }
    }
    __syncthreads();
    for (int t = tid; t < NBUCK; t += 256)
      lcur[t] = t * BUCK_CAP + atomicAdd(&cursor[t], hist[t]);
    __syncthreads();
#pragma unroll
    for (int c = 0; c < 2; c++) {
      if (cvalid[c]) {
#pragma unroll
        for (int j = 0; j < 4; j++) {
          const unsigned pk = packed[c * 4 + j];
          const int slot = atomicAdd(&lcur[pk >> 24], 1);
          routed[slot] = pk;
        }
      }
    }
  }
}

__global__ __launch_bounds__(256) void k_bsort_gemm128(
    const unsigned* __restrict__ routed, const int* __restrict__ cursor,
    int* __restrict__ counts, int* __restrict__ start,
    int* __restrict__ sorted_src, const float* __restrict__ X,
    const unsigned short* __restrict__ Wph,
    const unsigned short* __restrict__ Wpl, unsigned short* __restrict__ Hs) {
  __shared__ unsigned ebuf[BUCK_CAP];
  __shared__ int h2[256];
  __shared__ int c2[256];
  const int tid = threadIdx.x;
  if (blockIdx.x < NBUCK) {
    const int b = blockIdx.x;
    const int n = cursor[b];
    for (int i = tid; i < n; i += 256) ebuf[i] = routed[b * BUCK_CAP + i];
    h2[tid] = 0;
    __syncthreads();
    for (int i = tid; i < n; i += 256)
      atomicAdd(&h2[(ebuf[i] >> 16) & 255], 1);
    __syncthreads();
    const int own = h2[tid];
    for (int s = 1; s < 256; s <<= 1) {
      const int t = (tid >= s) ? h2[tid - s] : 0;
      __syncthreads();
      h2[tid] += t;
      __syncthreads();
    }
    const int pfx = h2[tid] - own;
    c2[tid] = pfx;
    const int d = b * 256 + tid;
    if (d < N_NODES) {
      counts[d] = own;
      start[d] = b * BUCK_CAP + pfx;
    }
    __syncthreads();
    for (int i = tid; i < n; i += 256) {
      const unsigned pk = ebuf[i];
      const int r = atomicAdd(&c2[(pk >> 16) & 255], 1);
      sorted_src[b * BUCK_CAP + r] = (int)(pk & 0xFFFFu);
    }
  } else {
    const int wtile = (blockIdx.x - NBUCK) * 4 + (tid >> 6);
    if (wtile < M_TILES) gemm_body<128>(wtile, tid & 63, X, Wph, Wpl, Hs);
  }
}

__global__ __launch_bounds__(256) void k_agg128_gemm64(
    const unsigned* __restrict__ Hb, const int* __restrict__ counts,
    const int* __restrict__ start, const int* __restrict__ sorted_src,
    const float* __restrict__ bias, const unsigned short* __restrict__ Wph,
    const unsigned short* __restrict__ Wpl, unsigned short* __restrict__ Hs) {
  __shared__ float a1s[16][132];
  const int lane = threadIdx.x & 63;
  const int wave = threadIdx.x >> 6;
  const int h = lane >> 5;
  const int c = lane & 31;
  const uint2* __restrict__ Hb2 = (const uint2*)Hb;
  const float4 bb = ((const float4*)bias)[c];
  const int vbase = blockIdx.x * 16 + wave * 4;

#pragma unroll
  for (int p = 0; p < 2; p++) {
    const int v = vbase + 2 * p + h;
    const int deg = counts[v];
    const int e0 = start[v];
    const float dv = rsqrtf((float)deg + 1.0f);
    const uint2 gs = Hb2[(size_t)v * 32 + c];
    int si = 0;
    float wi = 0.f;
    if (c < deg) {
      si = sorted_src[e0 + c];
      wi = rsqrtf((float)counts[si] + 1.0f) * dv;
    }
    const int dA = __shfl(deg, 0);
    const int dB = __shfl(deg, 32);
    const int mm = max(dA, dB);
    const int m = min(mm, 32);
    const float dv2 = dv * dv;
    float a0 = bf16_lo(gs.x) * dv2;
    float a1 = bf16_hi(gs.x) * dv2;
    float a2 = bf16_lo(gs.y) * dv2;
    float a3 = bf16_hi(gs.y) * dv2;

    for (int j = 0; j < m; j += 8) {
      int s[8];
      float w[8];
      uint2 g[8];
#pragma unroll
      for (int t = 0; t < 8; t++) {
        s[t] = __shfl(si, (lane & 32) | (j + t));
        w[t] = __shfl(wi, (lane & 32) | (j + t));
      }
#pragma unroll
      for (int t = 0; t < 8; t++) g[t] = Hb2[(size_t)s[t] * 32 + c];
#pragma unroll
      for (int t = 0; t < 8; t++) {
        a0 += bf16_lo(g[t].x) * w[t];
        a1 += bf16_hi(g[t].x) * w[t];
        a2 += bf16_lo(g[t].y) * w[t];
        a3 += bf16_hi(g[t].y) * w[t];
      }
    }
    for (int base = 32; base < mm; base += 32) {
      int sit = 0;
      float wit = 0.f;
      if (base + c < deg) {
        sit = sorted_src[e0 + base + c];
        wit = rsqrtf((float)counts[sit] + 1.0f) * dv;
      }
      const int lim = min(32, mm - base);
      for (int k = 0; k < lim; k++) {
        const int s = __shfl(sit, (lane & 32) | k);
        const float w = __shfl(wit, (lane & 32) | k);
        const uint2 g = Hb2[(size_t)s * 32 + c];
        a0 += bf16_lo(g.x) * w;
        a1 += bf16_hi(g.x) * w;
        a2 += bf16_lo(g.y) * w;
        a3 += bf16_hi(g.y) * w;
      }
    }
    float4 r;
    r.x = fmaxf(a0 + bb.x, 0.f);
    r.y = fmaxf(a1 + bb.y, 0.f);
    r.z = fmaxf(a2 + bb.z, 0.f);
    r.w = fmaxf(a3 + bb.w, 0.f);
    *(float4*)&a1s[wave * 4 + 2 * p + h][c * 4] = r;
  }
  __syncthreads();

  const int ct = wave;
  const int m = lane & 15;
  const int q = lane >> 4;
  f32x4 acc = {0.f, 0.f, 0.f, 0.f};
#pragma unroll
  for (int ks = 0; ks < 4; ks++) {
    bf16x8 ah, al;
    split8(&a1s[m][ks * 32 + q * 8], ah, al);
    const size_t bo = ((size_t)(ct * 4 + ks) * 64 + lane) * 8;
    const bf16x8 bh = *(const bf16x8*)(Wph + bo);
    const bf16x8 bl = *(const bf16x8*)(Wpl + bo);
    acc = __builtin_amdgcn_mfma_f32_16x16x32_bf16(ah, bh, acc, 0, 0, 0);
    acc = __builtin_amdgcn_mfma_f32_16x16x32_bf16(al, bh, acc, 0, 0, 0);
    acc = __builtin_amdgcn_mfma_f32_16x16x32_bf16(ah, bl, acc, 0, 0, 0);
  }
#pragma unroll
  for (int r = 0; r < 4; r++) {
    const int orow = blockIdx.x * 16 + q * 4 + r;
    Hs[(size_t)orow * 64 + ct * 16 + m] = f32_to_bf16(acc[r]);
  }
}

__global__ __launch_bounds__(256) void k_agg64(
    const unsigned* __restrict__ Hb, const int* __restrict__ counts,
    const int* __restrict__ start, const int* __restrict__ sorted_src,
    const float* __restrict__ bias, float* __restrict__ out) {
  const int lane = threadIdx.x & 63;
  const int wave = threadIdx.x >> 6;
  const int qq = lane >> 4;
  const int c = lane & 15;
  const uint2* __restrict__ Hb2 = (const uint2*)Hb;
  const float4 bb = ((const float4*)bias)[c];

  const int v = blockIdx.x * 16 + wave * 4 + qq;
  const int deg = counts[v];
  const int e0 = start[v];
  const float dv = rsqrtf((float)deg + 1.0f);
  const uint2 gs = Hb2[(size_t)v * 16 + c];
  int si0 = 0, si1 = 0;
  float wi0 = 0.f, wi1 = 0.f;
  if (c < deg) {
    si0 = sorted_src[e0 + c];
    wi0 = rsqrtf((float)counts[si0] + 1.0f) * dv;
  }
  if (c + 16 < deg) {
    si1 = sorted_src[e0 + c + 16];
    wi1 = rsqrtf((float)counts[si1] + 1.0f) * dv;
  }
  const int d0 = __shfl(deg, 0);
  const int d1 = __shfl(deg, 16);
  const int d2 = __shfl(deg, 32);
  const int d3 = __shfl(deg, 48);
  const int mm = max(max(d0, d1), max(d2, d3));
  const int m = min(mm, 32);
  const float dv2 = dv * dv;
  float a0 = bf16_lo(gs.x) * dv2;
  float a1 = bf16_hi(gs.x) * dv2;
  float a2 = bf16_lo(gs.y) * dv2;
  float a3 = bf16_hi(gs.y) * dv2;

#pragma unroll
  for (int jb = 0; jb < 4; jb++) {
    if (jb * 8 < m) {
      int s[8];
      float w[8];
      uint2 g[8];
#pragma unroll
      for (int t = 0; t < 8; t++) {
        const int e = jb * 8 + t;
        const int srcl = (lane & 48) | (e & 15);
        s[t] = __shfl((jb < 2) ? si0 : si1, srcl);
        w[t] = __shfl((jb < 2) ? wi0 : wi1, srcl);
      }
#pragma unroll
      for (int t = 0; t < 8; t++) g[t] = Hb2[(size_t)s[t] * 16 + c];
#pragma unroll
      for (int t = 0; t < 8; t++) {
        a0 += bf16_lo(g[t].x) * w[t];
        a1 += bf16_hi(g[t].x) * w[t];
        a2 += bf16_lo(g[t].y) * w[t];
        a3 += bf16_hi(g[t].y) * w[t];
      }
    }
  }
  for (int base = 32; base < mm; base += 16) {
    int sit = 0;
    float wit = 0.f;
    if (base + c < deg) {
      sit = sorted_src[e0 + base + c];
      wit = rsqrtf((float)counts[sit] + 1.0f) * dv;
    }
    const int lim = min(16, mm - base);
    for (int k = 0; k < lim; k++) {
      const int s = __shfl(sit, (lane & 48) | k);
      const float w = __shfl(wit, (lane & 48) | k);
      const uint2 g = Hb2[(size_t)s * 16 + c];
      a0 += bf16_lo(g.x) * w;
      a1 += bf16_hi(g.x) * w;
      a2 += bf16_lo(g.y) * w;
      a3 += bf16_hi(g.y) * w;
    }
  }
  float4 r;
  r.x = a0 + bb.x;
  r.y = a1 + bb.y;
  r.z = a2 + bb.z;
  r.w = a3 + bb.w;
  ((float4*)out)[(size_t)v * 16 + c] = r;
}

// ---------------- launch ----------------

extern "C" void kernel_launch(void* const* d_in, const int* in_sizes, int n_in,
                              void* d_out, int out_size, void* d_ws, size_t ws_size,
                              hipStream_t stream) {
  const float* x = (const float*)d_in[0];
  const int* ei = (const int*)d_in[1];
  const float* W1 = (const float*)d_in[2];
  const float* b1 = (const float*)d_in[3];
  const float* W2 = (const float*)d_in[4];
  const float* b2 = (const float*)d_in[5];
  const int* src = ei;
  const int* dst = ei + N_EDGES;
  float* outp = (float*)d_out;

  char* p = (char*)d_ws;
  auto alloc = [&](size_t bytes) {
    char* q = p;
    p += (bytes + 255) & ~(size_t)255;
    return q;
  };
  int* cursor = (int*)alloc((size_t)NBUCK * 4);
  unsigned* routed = (unsigned*)alloc((size_t)NBUCK * BUCK_CAP * 4);
  int* sorted_src = (int*)alloc((size_t)NBUCK * BUCK_CAP * 4);
  int* counts = (int*)alloc((size_t)N_NODES * 4);
  int* start = (int*)alloc((size_t)N_NODES * 4);
  unsigned short* w1h = (unsigned short*)alloc(16384 * 2);
  unsigned short* w1l = (unsigned short*)alloc(16384 * 2);
  unsigned short* w2h = (unsigned short*)alloc(8192 * 2);
  unsigned short* w2l = (unsigned short*)alloc(8192 * 2);
  unsigned short* h1b = (unsigned short*)alloc((size_t)N_NODES * 128 * 2);
  unsigned short* h2b = (unsigned short*)alloc((size_t)N_NODES * 64 * 2);

  // Capture-safe host-side queries, cached across calls.
  static int coop_grid = -1;  // total blocks for cooperative launch (0 = off)
  if (coop_grid < 0) {
    int coop_attr = 0;
    if (hipDeviceGetAttribute(&coop_attr, hipDeviceAttributeCooperativeLaunch,
                              0) != hipSuccess)
      coop_attr = 0;
    int num_cu = 0;
    if (hipDeviceGetAttribute(&num_cu, hipDeviceAttributeMultiprocessorCount,
                              0) != hipSuccess)
      num_cu = 0;
    int max_blk = 0;
    if (hipOccupancyMaxActiveBlocksPerMultiprocessor(&max_blk, k_mega, 256,
                                                     0) != hipSuccess)
      max_blk = 0;
    if (max_blk > 8) max_blk = 8;  // avoid excess grid.sync traffic
    coop_grid = (coop_attr != 0 && max_blk >= 1 && num_cu > 0)
                    ? max_blk * num_cu
                    : 0;
    if (coop_grid < 97) coop_grid = 0;  // P0 needs 97 blocks
  }

  bool launched = false;
  if (coop_grid > 0) {
    void* args[] = {&x,      &src,    &dst,        &W1,     &b1,    &W2,  &b2,
                    &cursor, &routed, &sorted_src, &counts, &start, &w1h, &w1l,
                    &w2h,    &w2l,    &h1b,        &h2b,    &outp};
    const hipError_t err = hipLaunchCooperativeKernel(
        (const void*)k_mega, dim3(coop_grid), dim3(256), args, 0, stream);
    launched = (err == hipSuccess);
  }

  if (!launched) {
    // fallback: verified round-1 multi-kernel pipeline
    hipMemsetAsync(cursor, 0, (size_t)NBUCK * 4, stream);
    hipLaunchKernelGGL(k_prep_route, dim3(96 + ROUTE_BLKS), dim3(256), 0,
                       stream, W1, W2, w1h, w1l, w2h, w2l, src, dst, cursor,
                       routed);
    hipLaunchKernelGGL(k_bsort_gemm128, dim3(NBUCK + GEMM_BLKS), dim3(256), 0,
                       stream, routed, cursor, counts, start, sorted_src, x,
                       w1h, w1l, h1b);
    hipLaunchKernelGGL(k_agg128_gemm64, dim3(M_TILES), dim3(256), 0, stream,
                       (const unsigned*)h1b, counts, start, sorted_src, b1,
                       w2h, w2l, h2b);
    hipLaunchKernelGGL(k_agg64, dim3(M_TILES), dim3(256), 0, stream,
                       (const unsigned*)h2b, counts, start, sorted_src, b2,
                       (float*)d_out);
  }
}

// Round 5
// 495.136 us; speedup vs baseline: 1.4716x; 1.4716x over previous
//
#include <hip/hip_runtime.h>
#include <hip/hip_cooperative_groups.h>
#include <cstddef>
#include <cstdint>

namespace cg = cooperative_groups;

#define N_NODES 50000
#define N_EDGES 600000
#define M_TILES 3125     // 50000 / 16 exactly
#define GEMM_UNITS 782   // ceil(3125/4)
#define GEMM_BLKS 782
#define NBUCK 196        // ceil(50000/256) coarse buckets (dst>>8)
#define BUCK_CAP 4096    // bucket total ~3072 +- 55
#define ROUTE_EDGES 2048 // edges routed per route unit
#define ROUTE_UNITS 293  // ceil(600000/2048)
#define ROUTE_BLKS 293

typedef short bf16x8 __attribute__((ext_vector_type(8)));
typedef float f32x4 __attribute__((ext_vector_type(4)));

// ---------------- bf16 helpers ----------------

__device__ __forceinline__ unsigned short f32_to_bf16(float x) {
  unsigned u = __float_as_uint(x);
  u += 0x7FFFu + ((u >> 16) & 1u);  // round-to-nearest-even
  return (unsigned short)(u >> 16);
}
__device__ __forceinline__ float bf16_to_f32(unsigned short h) {
  return __uint_as_float((unsigned)h << 16);
}
__device__ __forceinline__ float bf16_lo(unsigned g) {
  return __uint_as_float(g << 16);
}
__device__ __forceinline__ float bf16_hi(unsigned g) {
  return __uint_as_float(g & 0xFFFF0000u);
}

// Split 8 contiguous fp32 into bf16 hi + bf16 lo fragments (in-register).
__device__ __forceinline__ void split8(const float* __restrict__ p, bf16x8& hi,
                                       bf16x8& lo) {
  const float4 v0 = *(const float4*)p;
  const float4 v1 = *(const float4*)(p + 4);
  float v[8] = {v0.x, v0.y, v0.z, v0.w, v1.x, v1.y, v1.z, v1.w};
#pragma unroll
  for (int i = 0; i < 8; i++) {
    const unsigned short h = f32_to_bf16(v[i]);
    hi[i] = (short)h;
    lo[i] = (short)f32_to_bf16(v[i] - bf16_to_f32(h));
  }
}

// ---------------- MFMA GEMM body: H(bf16) = X[N,128](fp32) @ W[128,COUT] ---
template <int COUT>
__device__ __forceinline__ void gemm_body(const int wtile, const int lane,
                                          const float* __restrict__ X,
                                          const unsigned short* __restrict__ Wph,
                                          const unsigned short* __restrict__ Wpl,
                                          unsigned short* __restrict__ Hs) {
  constexpr int CT = COUT / 16;
  const int m = lane & 15;
  const int q = lane >> 4;

  f32x4 acc[CT];
#pragma unroll
  for (int ct = 0; ct < CT; ct++) acc[ct] = {0.f, 0.f, 0.f, 0.f};

  const float* xp = X + (size_t)(wtile * 16 + m) * 128 + q * 8;

#pragma unroll
  for (int ks = 0; ks < 4; ks++) {
    bf16x8 ah, al;
    split8(xp + ks * 32, ah, al);
#pragma unroll
    for (int ct = 0; ct < CT; ct++) {
      const size_t bo = ((size_t)(ct * 4 + ks) * 64 + lane) * 8;
      const bf16x8 bh = *(const bf16x8*)(Wph + bo);
      const bf16x8 bl = *(const bf16x8*)(Wpl + bo);
      acc[ct] = __builtin_amdgcn_mfma_f32_16x16x32_bf16(ah, bh, acc[ct], 0, 0, 0);
      acc[ct] = __builtin_amdgcn_mfma_f32_16x16x32_bf16(al, bh, acc[ct], 0, 0, 0);
      acc[ct] = __builtin_amdgcn_mfma_f32_16x16x32_bf16(ah, bl, acc[ct], 0, 0, 0);
    }
  }
  // C/D layout: col = lane&15 (=m), row = q*4 + r
#pragma unroll
  for (int ct = 0; ct < CT; ct++) {
#pragma unroll
    for (int r = 0; r < 4; r++) {
      const int orow = wtile * 16 + q * 4 + r;
      Hs[(size_t)orow * COUT + ct * 16 + m] = f32_to_bf16(acc[ct][r]);
    }
  }
}

// ---------------- W-pack body (shared by mega P0 and fallback) ----------
__device__ __forceinline__ void wpack_body(const int i,
                                           const float* __restrict__ W1,
                                           const float* __restrict__ W2,
                                           unsigned short* __restrict__ w1h,
                                           unsigned short* __restrict__ w1l,
                                           unsigned short* __restrict__ w2h,
                                           unsigned short* __restrict__ w2l) {
  // Wp[((ct*4+ks)*64+lane)*8+j] = W[(ks*32+(lane>>4)*8+j)*COUT + ct*16+(lane&15)]
  const float* W;
  unsigned short *wh, *wl;
  int o, cout;
  if (i < 16384) {
    W = W1; wh = w1h; wl = w1l; o = i; cout = 128;
  } else {
    W = W2; wh = w2h; wl = w2l; o = i - 16384; cout = 64;
  }
  const int j = o & 7;
  const int ln = (o >> 3) & 63;
  const int t = o >> 9;  // ct*4 + ks
  const int ks = t & 3;
  const int ct = t >> 2;
  const int k = ks * 32 + (ln >> 4) * 8 + j;
  const int n = ct * 16 + (ln & 15);
  const float v = W[k * cout + n];
  const unsigned short h = f32_to_bf16(v);
  wh[o] = h;
  wl[o] = f32_to_bf16(v - bf16_to_f32(h));
}

// ================== single cooperative kernel: 5 phases ==================
// P0: W-pack (96 units) + cursor zero.
// P1: edge routing (293 units) || GEMM1 (782 units), grid-stride.
// P2: per-bucket counting sort (196 units), no LDS staging (8.4K LDS).
// P3: layer-1 aggregation + GEMM2 (3125 units, grid-stride).
// P4: layer-2 aggregation (3125 units, grid-stride).
// __launch_bounds__(256,2): round-4's (256,4) clamped VGPRs to 64 and the
// gather loops spilled (WRITE_SIZE 42->121 MB, 5x regression). (256,2)
// restores ~116 VGPRs; at <=128 VGPR the HW still fits 4 waves/SIMD, so the
// occupancy QUERY (not the bound) decides the grid: expect 4 blocks/CU.
__global__ __launch_bounds__(256, 2) void k_mega(
    const float* __restrict__ X, const int* __restrict__ src,
    const int* __restrict__ dst, const float* __restrict__ W1,
    const float* __restrict__ b1, const float* __restrict__ W2,
    const float* __restrict__ b2, int* __restrict__ cursor,
    unsigned* __restrict__ routed, int* __restrict__ sorted_src,
    int* __restrict__ counts, int* __restrict__ start,
    unsigned short* __restrict__ w1h, unsigned short* __restrict__ w1l,
    unsigned short* __restrict__ w2h, unsigned short* __restrict__ w2l,
    unsigned short* __restrict__ h1b, unsigned short* __restrict__ h2b,
    float* __restrict__ out) {
  __shared__ __align__(16) unsigned char smem[16 * 132 * 4];  // 8448 B union
  cg::grid_group grid = cg::this_grid();
  const int tid = threadIdx.x;
  const int bid = blockIdx.x;
  const int nblk = gridDim.x;
  const int lane = tid & 63;
  const int wave = tid >> 6;

  // ---------------- P0: W-pack + cursor zero ----------------
  if (bid < 96) {
    wpack_body(bid * 256 + tid, W1, W2, w1h, w1l, w2h, w2l);
  } else if (bid == 96) {
    if (tid < NBUCK) cursor[tid] = 0;
  }
  __threadfence();
  grid.sync();
  __threadfence();

  // ---------------- P1: routing || GEMM1 ----------------
  for (int u = bid; u < ROUTE_UNITS + GEMM_UNITS; u += nblk) {
    if (u < ROUTE_UNITS) {
      int* hist = (int*)smem;
      int* lcur = hist + NBUCK;
      for (int t = tid; t < NBUCK; t += 256) hist[t] = 0;
      __syncthreads();
      unsigned packed[8];
      bool cvalid[2];
      const int base = u * ROUTE_EDGES;
#pragma unroll
      for (int c = 0; c < 2; c++) {
        const int i4 = base + c * 1024 + tid * 4;  // always mult of 4
        cvalid[c] = (i4 < N_EDGES);
        if (cvalid[c]) {
          const int4 d4 = *(const int4*)(dst + i4);
          const int4 s4 = *(const int4*)(src + i4);
          packed[c * 4 + 0] = ((unsigned)d4.x << 16) | (unsigned)s4.x;
          packed[c * 4 + 1] = ((unsigned)d4.y << 16) | (unsigned)s4.y;
          packed[c * 4 + 2] = ((unsigned)d4.z << 16) | (unsigned)s4.z;
          packed[c * 4 + 3] = ((unsigned)d4.w << 16) | (unsigned)s4.w;
#pragma unroll
          for (int j = 0; j < 4; j++)
            atomicAdd(&hist[packed[c * 4 + j] >> 24], 1);  // LDS atomic
        }
      }
      __syncthreads();
      // one device atomic per bucket: claim contiguous range in the region
      for (int t = tid; t < NBUCK; t += 256)
        lcur[t] = t * BUCK_CAP + atomicAdd(&cursor[t], hist[t]);
      __syncthreads();
#pragma unroll
      for (int c = 0; c < 2; c++) {
        if (cvalid[c]) {
#pragma unroll
          for (int j = 0; j < 4; j++) {
            const unsigned pk = packed[c * 4 + j];
            const int slot = atomicAdd(&lcur[pk >> 24], 1);  // LDS atomic
            routed[slot] = pk;
          }
        }
      }
      __syncthreads();  // hist/lcur reuse guard across loop iterations
    } else {
      const int wtile = (u - ROUTE_UNITS) * 4 + wave;
      if (wtile < M_TILES) gemm_body<128>(wtile, lane, X, w1h, w1l, h1b);
    }
  }
  __threadfence();
  grid.sync();
  __threadfence();

  // ---------------- P2: per-bucket counting sort (no LDS staging) -------
  for (int b = bid; b < NBUCK; b += nblk) {
    int* h2 = (int*)smem;
    int* c2 = h2 + 256;
    const int n = cursor[b];  // count-based
    const unsigned* __restrict__ rb = routed + b * BUCK_CAP;
    h2[tid] = 0;
    __syncthreads();
    for (int i = tid; i < n; i += 256)
      atomicAdd(&h2[(rb[i] >> 16) & 255], 1);
    __syncthreads();
    const int own = h2[tid];
    for (int s = 1; s < 256; s <<= 1) {
      const int t = (tid >= s) ? h2[tid - s] : 0;
      __syncthreads();
      h2[tid] += t;
      __syncthreads();
    }
    const int pfx = h2[tid] - own;  // exclusive prefix
    c2[tid] = pfx;
    const int d = b * 256 + tid;
    if (d < N_NODES) {
      counts[d] = own;
      start[d] = b * BUCK_CAP + pfx;
    }
    __syncthreads();
    for (int i = tid; i < n; i += 256) {
      const unsigned pk = rb[i];  // second read: L2-hot
      const int r = atomicAdd(&c2[(pk >> 16) & 255], 1);  // LDS atomic
      sorted_src[b * BUCK_CAP + r] = (int)(pk & 0xFFFFu);
    }
    __syncthreads();  // h2/c2 reuse guard
  }
  __threadfence();
  grid.sync();
  __threadfence();

  // ---------------- P3: layer-1 aggregation + GEMM2 ----------------
  // Half-wave (32 lanes x uint2 = full 256 B row) per node; each load
  // gathers edge rows for TWO nodes. Accumulation order identical to the
  // per-edge version -> bitwise-identical results.
  {
    float(*a1s)[132] = (float(*)[132])smem;  // 16 x 132 fp32, +4 pad
    const int h = lane >> 5;  // half id: which node of the pair
    const int c = lane & 31;  // uint2 column within the 256 B row
    const uint2* __restrict__ Hb2 = (const uint2*)h1b;
    const float4 bb = ((const float4*)b1)[c];

    for (int u = bid; u < M_TILES; u += nblk) {
      const int vbase = u * 16 + wave * 4;
#pragma unroll
      for (int p = 0; p < 2; p++) {
        const int v = vbase + 2 * p + h;
        const int deg = counts[v];
        const int e0 = start[v];
        const float dv = rsqrtf((float)deg + 1.0f);
        const uint2 gs = Hb2[(size_t)v * 32 + c];
        int si = 0;
        float wi = 0.f;
        if (c < deg) {
          si = sorted_src[e0 + c];
          wi = rsqrtf((float)counts[si] + 1.0f) * dv;
        }
        const int dA = __shfl(deg, 0);
        const int dB = __shfl(deg, 32);
        const int mm = max(dA, dB);
        const int m = min(mm, 32);
        const float dv2 = dv * dv;
        float a0 = bf16_lo(gs.x) * dv2;
        float a1 = bf16_hi(gs.x) * dv2;
        float a2 = bf16_lo(gs.y) * dv2;
        float a3 = bf16_hi(gs.y) * dv2;

        for (int j = 0; j < m; j += 8) {
          int s[8];
          float w[8];
          uint2 g[8];
#pragma unroll
          for (int t = 0; t < 8; t++) {
            s[t] = __shfl(si, (lane & 32) | (j + t));
            w[t] = __shfl(wi, (lane & 32) | (j + t));
          }
#pragma unroll
          for (int t = 0; t < 8; t++) g[t] = Hb2[(size_t)s[t] * 32 + c];
#pragma unroll
          for (int t = 0; t < 8; t++) {
            a0 += bf16_lo(g[t].x) * w[t];
            a1 += bf16_hi(g[t].x) * w[t];
            a2 += bf16_lo(g[t].y) * w[t];
            a3 += bf16_hi(g[t].y) * w[t];
          }
        }
        // rare tail: deg > 32 (max in-degree ~35 for this input)
        for (int base = 32; base < mm; base += 32) {
          int sit = 0;
          float wit = 0.f;
          if (base + c < deg) {
            sit = sorted_src[e0 + base + c];
            wit = rsqrtf((float)counts[sit] + 1.0f) * dv;
          }
          const int lim = min(32, mm - base);
          for (int k = 0; k < lim; k++) {
            const int s = __shfl(sit, (lane & 32) | k);
            const float w = __shfl(wit, (lane & 32) | k);
            const uint2 g = Hb2[(size_t)s * 32 + c];
            a0 += bf16_lo(g.x) * w;
            a1 += bf16_hi(g.x) * w;
            a2 += bf16_lo(g.y) * w;
            a3 += bf16_hi(g.y) * w;
          }
        }
        float4 r;
        r.x = fmaxf(a0 + bb.x, 0.f);
        r.y = fmaxf(a1 + bb.y, 0.f);
        r.z = fmaxf(a2 + bb.z, 0.f);
        r.w = fmaxf(a3 + bb.w, 0.f);
        *(float4*)&a1s[wave * 4 + 2 * p + h][c * 4] = r;  // 528 B rows
      }
      __syncthreads();

      // GEMM2: each wave computes one 16x16 column tile of h2 = a1 @ W2
      const int ct = wave;
      const int m2 = lane & 15;
      const int q = lane >> 4;
      f32x4 acc = {0.f, 0.f, 0.f, 0.f};
#pragma unroll
      for (int ks = 0; ks < 4; ks++) {
        bf16x8 ah, al;
        split8(&a1s[m2][ks * 32 + q * 8], ah, al);
        const size_t bo = ((size_t)(ct * 4 + ks) * 64 + lane) * 8;
        const bf16x8 bh = *(const bf16x8*)(w2h + bo);
        const bf16x8 bl = *(const bf16x8*)(w2l + bo);
        acc = __builtin_amdgcn_mfma_f32_16x16x32_bf16(ah, bh, acc, 0, 0, 0);
        acc = __builtin_amdgcn_mfma_f32_16x16x32_bf16(al, bh, acc, 0, 0, 0);
        acc = __builtin_amdgcn_mfma_f32_16x16x32_bf16(ah, bl, acc, 0, 0, 0);
      }
#pragma unroll
      for (int r = 0; r < 4; r++) {
        const int orow = u * 16 + q * 4 + r;
        h2b[(size_t)orow * 64 + ct * 16 + m2] = f32_to_bf16(acc[r]);
      }
      __syncthreads();  // a1s reuse guard before next unit
    }
  }
  __threadfence();
  grid.sync();
  __threadfence();

  // ---------------- P4: layer-2 aggregation (COUT=64, no relu) ----------
  // Quarter-wave (16 lanes x uint2 = full 128 B row) per node; one load
  // gathers edge rows for FOUR nodes. Accumulation order identical.
  {
    const int qq = lane >> 4;  // quarter id: which node
    const int c = lane & 15;   // uint2 column within the 128 B row
    const uint2* __restrict__ Hb2 = (const uint2*)h2b;
    const float4 bb = ((const float4*)b2)[c];

    for (int u = bid; u < M_TILES; u += nblk) {
      const int v = u * 16 + wave * 4 + qq;
      const int deg = counts[v];
      const int e0 = start[v];
      const float dv = rsqrtf((float)deg + 1.0f);
      const uint2 gs = Hb2[(size_t)v * 16 + c];
      int si0 = 0, si1 = 0;
      float wi0 = 0.f, wi1 = 0.f;
      if (c < deg) {
        si0 = sorted_src[e0 + c];
        wi0 = rsqrtf((float)counts[si0] + 1.0f) * dv;
      }
      if (c + 16 < deg) {
        si1 = sorted_src[e0 + c + 16];
        wi1 = rsqrtf((float)counts[si1] + 1.0f) * dv;
      }
      const int d0 = __shfl(deg, 0);
      const int d1 = __shfl(deg, 16);
      const int d2 = __shfl(deg, 32);
      const int d3 = __shfl(deg, 48);
      const int mm = max(max(d0, d1), max(d2, d3));
      const int m = min(mm, 32);
      const float dv2 = dv * dv;
      float a0 = bf16_lo(gs.x) * dv2;
      float a1 = bf16_hi(gs.x) * dv2;
      float a2 = bf16_lo(gs.y) * dv2;
      float a3 = bf16_hi(gs.y) * dv2;

#pragma unroll
      for (int jb = 0; jb < 4; jb++) {
        if (jb * 8 < m) {
          int s[8];
          float w[8];
          uint2 g[8];
#pragma unroll
          for (int t = 0; t < 8; t++) {
            const int e = jb * 8 + t;  // 0..31
            const int srcl = (lane & 48) | (e & 15);
            s[t] = __shfl((jb < 2) ? si0 : si1, srcl);
            w[t] = __shfl((jb < 2) ? wi0 : wi1, srcl);
          }
#pragma unroll
          for (int t = 0; t < 8; t++) g[t] = Hb2[(size_t)s[t] * 16 + c];
#pragma unroll
          for (int t = 0; t < 8; t++) {
            a0 += bf16_lo(g[t].x) * w[t];
            a1 += bf16_hi(g[t].x) * w[t];
            a2 += bf16_lo(g[t].y) * w[t];
            a3 += bf16_hi(g[t].y) * w[t];
          }
        }
      }
      // rare tail: deg > 32
      for (int base = 32; base < mm; base += 16) {
        int sit = 0;
        float wit = 0.f;
        if (base + c < deg) {
          sit = sorted_src[e0 + base + c];
          wit = rsqrtf((float)counts[sit] + 1.0f) * dv;
        }
        const int lim = min(16, mm - base);
        for (int k = 0; k < lim; k++) {
          const int s = __shfl(sit, (lane & 48) | k);
          const float w = __shfl(wit, (lane & 48) | k);
          const uint2 g = Hb2[(size_t)s * 16 + c];
          a0 += bf16_lo(g.x) * w;
          a1 += bf16_hi(g.x) * w;
          a2 += bf16_lo(g.y) * w;
          a3 += bf16_hi(g.y) * w;
        }
      }
      float4 r;
      r.x = a0 + bb.x;
      r.y = a1 + bb.y;
      r.z = a2 + bb.z;
      r.w = a3 + bb.w;
      ((float4*)out)[(size_t)v * 16 + c] = r;
    }
  }
}

// ================== fallback pipeline (round-1 verified, 152.9 us) =======

__global__ __launch_bounds__(256) void k_prep_route(
    const float* __restrict__ W1, const float* __restrict__ W2,
    unsigned short* __restrict__ w1h, unsigned short* __restrict__ w1l,
    unsigned short* __restrict__ w2h, unsigned short* __restrict__ w2l,
    const int* __restrict__ src, const int* __restrict__ dst,
    int* __restrict__ cursor, unsigned* __restrict__ routed) {
  __shared__ int hist[NBUCK];
  __shared__ int lcur[NBUCK];
  const int tid = threadIdx.x;
  if (blockIdx.x < 96) {
    wpack_body(blockIdx.x * 256 + tid, W1, W2, w1h, w1l, w2h, w2l);
  } else {
    const int rb = blockIdx.x - 96;
    for (int t = tid; t < NBUCK; t += 256) hist[t] = 0;
    __syncthreads();
    unsigned packed[8];
    bool cvalid[2];
    const int base = rb * ROUTE_EDGES;
#pragma unroll
    for (int c = 0; c < 2; c++) {
      const int i4 = base + c * 1024 + tid * 4;
      cvalid[c] = (i4 < N_EDGES);
      if (cvalid[c]) {
        const int4 d4 = *(const int4*)(dst + i4);
        const int4 s4 = *(const int4*)(src + i4);
        packed[c * 4 + 0] = ((unsigned)d4.x << 16) | (unsigned)s4.x;
        packed[c * 4 + 1] = ((unsigned)d4.y << 16) | (unsigned)s4.y;
        packed[c * 4 + 2] = ((unsigned)d4.z << 16) | (unsigned)s4.z;
        packed[c * 4 + 3] = ((unsigned)d4.w << 16) | (unsigned)s4.w;
#pragma unroll
        for (int j = 0; j < 4; j++)
          atomicAdd(&hist[packed[c * 4 + j] >> 24], 1);
      }
    }
    __syncthreads();
    for (int t = tid; t < NBUCK; t += 256)
      lcur[t] = t * BUCK_CAP + atomicAdd(&cursor[t], hist[t]);
    __syncthreads();
#pragma unroll
    for (int c = 0; c < 2; c++) {
      if (cvalid[c]) {
#pragma unroll
        for (int j = 0; j < 4; j++) {
          const unsigned pk = packed[c * 4 + j];
          const int slot = atomicAdd(&lcur[pk >> 24], 1);
          routed[slot] = pk;
        }
      }
    }
  }
}

__global__ __launch_bounds__(256) void k_bsort_gemm128(
    const unsigned* __restrict__ routed, const int* __restrict__ cursor,
    int* __restrict__ counts, int* __restrict__ start,
    int* __restrict__ sorted_src, const float* __restrict__ X,
    const unsigned short* __restrict__ Wph,
    const unsigned short* __restrict__ Wpl, unsigned short* __restrict__ Hs) {
  __shared__ unsigned ebuf[BUCK_CAP];
  __shared__ int h2[256];
  __shared__ int c2[256];
  const int tid = threadIdx.x;
  if (blockIdx.x < NBUCK) {
    const int b = blockIdx.x;
    const int n = cursor[b];
    for (int i = tid; i < n; i += 256) ebuf[i] = routed[b * BUCK_CAP + i];
    h2[tid] = 0;
    __syncthreads();
    for (int i = tid; i < n; i += 256)
      atomicAdd(&h2[(ebuf[i] >> 16) & 255], 1);
    __syncthreads();
    const int own = h2[tid];
    for (int s = 1; s < 256; s <<= 1) {
      const int t = (tid >= s) ? h2[tid - s] : 0;
      __syncthreads();
      h2[tid] += t;
      __syncthreads();
    }
    const int pfx = h2[tid] - own;
    c2[tid] = pfx;
    const int d = b * 256 + tid;
    if (d < N_NODES) {
      counts[d] = own;
      start[d] = b * BUCK_CAP + pfx;
    }
    __syncthreads();
    for (int i = tid; i < n; i += 256) {
      const unsigned pk = ebuf[i];
      const int r = atomicAdd(&c2[(pk >> 16) & 255], 1);
      sorted_src[b * BUCK_CAP + r] = (int)(pk & 0xFFFFu);
    }
  } else {
    const int wtile = (blockIdx.x - NBUCK) * 4 + (tid >> 6);
    if (wtile < M_TILES) gemm_body<128>(wtile, tid & 63, X, Wph, Wpl, Hs);
  }
}

__global__ __launch_bounds__(256) void k_agg128_gemm64(
    const unsigned* __restrict__ Hb, const int* __restrict__ counts,
    const int* __restrict__ start, const int* __restrict__ sorted_src,
    const float* __restrict__ bias, const unsigned short* __restrict__ Wph,
    const unsigned short* __restrict__ Wpl, unsigned short* __restrict__ Hs) {
  __shared__ float a1s[16][132];
  const int lane = threadIdx.x & 63;
  const int wave = threadIdx.x >> 6;
  const int h = lane >> 5;
  const int c = lane & 31;
  const uint2* __restrict__ Hb2 = (const uint2*)Hb;
  const float4 bb = ((const float4*)bias)[c];
  const int vbase = blockIdx.x * 16 + wave * 4;

#pragma unroll
  for (int p = 0; p < 2; p++) {
    const int v = vbase + 2 * p + h;
    const int deg = counts[v];
    const int e0 = start[v];
    const float dv = rsqrtf((float)deg + 1.0f);
    const uint2 gs = Hb2[(size_t)v * 32 + c];
    int si = 0;
    float wi = 0.f;
    if (c < deg) {
      si = sorted_src[e0 + c];
      wi = rsqrtf((float)counts[si] + 1.0f) * dv;
    }
    const int dA = __shfl(deg, 0);
    const int dB = __shfl(deg, 32);
    const int mm = max(dA, dB);
    const int m = min(mm, 32);
    const float dv2 = dv * dv;
    float a0 = bf16_lo(gs.x) * dv2;
    float a1 = bf16_hi(gs.x) * dv2;
    float a2 = bf16_lo(gs.y) * dv2;
    float a3 = bf16_hi(gs.y) * dv2;

    for (int j = 0; j < m; j += 8) {
      int s[8];
      float w[8];
      uint2 g[8];
#pragma unroll
      for (int t = 0; t < 8; t++) {
        s[t] = __shfl(si, (lane & 32) | (j + t));
        w[t] = __shfl(wi, (lane & 32) | (j + t));
      }
#pragma unroll
      for (int t = 0; t < 8; t++) g[t] = Hb2[(size_t)s[t] * 32 + c];
#pragma unroll
      for (int t = 0; t < 8; t++) {
        a0 += bf16_lo(g[t].x) * w[t];
        a1 += bf16_hi(g[t].x) * w[t];
        a2 += bf16_lo(g[t].y) * w[t];
        a3 += bf16_hi(g[t].y) * w[t];
      }
    }
    for (int base = 32; base < mm; base += 32) {
      int sit = 0;
      float wit = 0.f;
      if (base + c < deg) {
        sit = sorted_src[e0 + base + c];
        wit = rsqrtf((float)counts[sit] + 1.0f) * dv;
      }
      const int lim = min(32, mm - base);
      for (int k = 0; k < lim; k++) {
        const int s = __shfl(sit, (lane & 32) | k);
        const float w = __shfl(wit, (lane & 32) | k);
        const uint2 g = Hb2[(size_t)s * 32 + c];
        a0 += bf16_lo(g.x) * w;
        a1 += bf16_hi(g.x) * w;
        a2 += bf16_lo(g.y) * w;
        a3 += bf16_hi(g.y) * w;
      }
    }
    float4 r;
    r.x = fmaxf(a0 + bb.x, 0.f);
    r.y = fmaxf(a1 + bb.y, 0.f);
    r.z = fmaxf(a2 + bb.z, 0.f);
    r.w = fmaxf(a3 + bb.w, 0.f);
    *(float4*)&a1s[wave * 4 + 2 * p + h][c * 4] = r;
  }
  __syncthreads();

  const int ct = wave;
  const int m = lane & 15;
  const int q = lane >> 4;
  f32x4 acc = {0.f, 0.f, 0.f, 0.f};
#pragma unroll
  for (int ks = 0; ks < 4; ks++) {
    bf16x8 ah, al;
    split8(&a1s[m][ks * 32 + q * 8], ah, al);
    const size_t bo = ((size_t)(ct * 4 + ks) * 64 + lane) * 8;
    const bf16x8 bh = *(const bf16x8*)(Wph + bo);
    const bf16x8 bl = *(const bf16x8*)(Wpl + bo);
    acc = __builtin_amdgcn_mfma_f32_16x16x32_bf16(ah, bh, acc, 0, 0, 0);
    acc = __builtin_amdgcn_mfma_f32_16x16x32_bf16(al, bh, acc, 0, 0, 0);
    acc = __builtin_amdgcn_mfma_f32_16x16x32_bf16(ah, bl, acc, 0, 0, 0);
  }
#pragma unroll
  for (int r = 0; r < 4; r++) {
    const int orow = blockIdx.x * 16 + q * 4 + r;
    Hs[(size_t)orow * 64 + ct * 16 + m] = f32_to_bf16(acc[r]);
  }
}

__global__ __launch_bounds__(256) void k_agg64(
    const unsigned* __restrict__ Hb, const int* __restrict__ counts,
    const int* __restrict__ start, const int* __restrict__ sorted_src,
    const float* __restrict__ bias, float* __restrict__ out) {
  const int lane = threadIdx.x & 63;
  const int wave = threadIdx.x >> 6;
  const int qq = lane >> 4;
  const int c = lane & 15;
  const uint2* __restrict__ Hb2 = (const uint2*)Hb;
  const float4 bb = ((const float4*)bias)[c];

  const int v = blockIdx.x * 16 + wave * 4 + qq;
  const int deg = counts[v];
  const int e0 = start[v];
  const float dv = rsqrtf((float)deg + 1.0f);
  const uint2 gs = Hb2[(size_t)v * 16 + c];
  int si0 = 0, si1 = 0;
  float wi0 = 0.f, wi1 = 0.f;
  if (c < deg) {
    si0 = sorted_src[e0 + c];
    wi0 = rsqrtf((float)counts[si0] + 1.0f) * dv;
  }
  if (c + 16 < deg) {
    si1 = sorted_src[e0 + c + 16];
    wi1 = rsqrtf((float)counts[si1] + 1.0f) * dv;
  }
  const int d0 = __shfl(deg, 0);
  const int d1 = __shfl(deg, 16);
  const int d2 = __shfl(deg, 32);
  const int d3 = __shfl(deg, 48);
  const int mm = max(max(d0, d1), max(d2, d3));
  const int m = min(mm, 32);
  const float dv2 = dv * dv;
  float a0 = bf16_lo(gs.x) * dv2;
  float a1 = bf16_hi(gs.x) * dv2;
  float a2 = bf16_lo(gs.y) * dv2;
  float a3 = bf16_hi(gs.y) * dv2;

#pragma unroll
  for (int jb = 0; jb < 4; jb++) {
    if (jb * 8 < m) {
      int s[8];
      float w[8];
      uint2 g[8];
#pragma unroll
      for (int t = 0; t < 8; t++) {
        const int e = jb * 8 + t;
        const int srcl = (lane & 48) | (e & 15);
        s[t] = __shfl((jb < 2) ? si0 : si1, srcl);
        w[t] = __shfl((jb < 2) ? wi0 : wi1, srcl);
      }
#pragma unroll
      for (int t = 0; t < 8; t++) g[t] = Hb2[(size_t)s[t] * 16 + c];
#pragma unroll
      for (int t = 0; t < 8; t++) {
        a0 += bf16_lo(g[t].x) * w[t];
        a1 += bf16_hi(g[t].x) * w[t];
        a2 += bf16_lo(g[t].y) * w[t];
        a3 += bf16_hi(g[t].y) * w[t];
      }
    }
  }
  for (int base = 32; base < mm; base += 16) {
    int sit = 0;
    float wit = 0.f;
    if (base + c < deg) {
      sit = sorted_src[e0 + base + c];
      wit = rsqrtf((float)counts[sit] + 1.0f) * dv;
    }
    const int lim = min(16, mm - base);
    for (int k = 0; k < lim; k++) {
      const int s = __shfl(sit, (lane & 48) | k);
      const float w = __shfl(wit, (lane & 48) | k);
      const uint2 g = Hb2[(size_t)s * 16 + c];
      a0 += bf16_lo(g.x) * w;
      a1 += bf16_hi(g.x) * w;
      a2 += bf16_lo(g.y) * w;
      a3 += bf16_hi(g.y) * w;
    }
  }
  float4 r;
  r.x = a0 + bb.x;
  r.y = a1 + bb.y;
  r.z = a2 + bb.z;
  r.w = a3 + bb.w;
  ((float4*)out)[(size_t)v * 16 + c] = r;
}

// ---------------- launch ----------------

extern "C" void kernel_launch(void* const* d_in, const int* in_sizes, int n_in,
                              void* d_out, int out_size, void* d_ws, size_t ws_size,
                              hipStream_t stream) {
  const float* x = (const float*)d_in[0];
  const int* ei = (const int*)d_in[1];
  const float* W1 = (const float*)d_in[2];
  const float* b1 = (const float*)d_in[3];
  const float* W2 = (const float*)d_in[4];
  const float* b2 = (const float*)d_in[5];
  const int* src = ei;
  const int* dst = ei + N_EDGES;
  float* outp = (float*)d_out;

  char* p = (char*)d_ws;
  auto alloc = [&](size_t bytes) {
    char* q = p;
    p += (bytes + 255) & ~(size_t)255;
    return q;
  };
  int* cursor = (int*)alloc((size_t)NBUCK * 4);
  unsigned* routed = (unsigned*)alloc((size_t)NBUCK * BUCK_CAP * 4);
  int* sorted_src = (int*)alloc((size_t)NBUCK * BUCK_CAP * 4);
  int* counts = (int*)alloc((size_t)N_NODES * 4);
  int* start = (int*)alloc((size_t)N_NODES * 4);
  unsigned short* w1h = (unsigned short*)alloc(16384 * 2);
  unsigned short* w1l = (unsigned short*)alloc(16384 * 2);
  unsigned short* w2h = (unsigned short*)alloc(8192 * 2);
  unsigned short* w2l = (unsigned short*)alloc(8192 * 2);
  unsigned short* h1b = (unsigned short*)alloc((size_t)N_NODES * 128 * 2);
  unsigned short* h2b = (unsigned short*)alloc((size_t)N_NODES * 64 * 2);

  // Capture-safe host-side queries, cached across calls.
  static int coop_grid = -1;  // total blocks for cooperative launch (0 = off)
  if (coop_grid < 0) {
    int coop_attr = 0;
    if (hipDeviceGetAttribute(&coop_attr, hipDeviceAttributeCooperativeLaunch,
                              0) != hipSuccess)
      coop_attr = 0;
    int num_cu = 0;
    if (hipDeviceGetAttribute(&num_cu, hipDeviceAttributeMultiprocessorCount,
                              0) != hipSuccess)
      num_cu = 0;
    int max_blk = 0;
    if (hipOccupancyMaxActiveBlocksPerMultiprocessor(&max_blk, k_mega, 256,
                                                     0) != hipSuccess)
      max_blk = 0;
    if (max_blk > 4) max_blk = 4;  // controlled TLP test: <=16 waves/CU
    coop_grid = (coop_attr != 0 && max_blk >= 1 && num_cu > 0)
                    ? max_blk * num_cu
                    : 0;
    if (coop_grid < 97) coop_grid = 0;  // P0 needs 97 blocks
  }

  bool launched = false;
  if (coop_grid > 0) {
    void* args[] = {&x,      &src,    &dst,        &W1,     &b1,    &W2,  &b2,
                    &cursor, &routed, &sorted_src, &counts, &start, &w1h, &w1l,
                    &w2h,    &w2l,    &h1b,        &h2b,    &outp};
    const hipError_t err = hipLaunchCooperativeKernel(
        (const void*)k_mega, dim3(coop_grid), dim3(256), args, 0, stream);
    launched = (err == hipSuccess);
  }

  if (!launched) {
    // fallback: verified round-1 multi-kernel pipeline
    hipMemsetAsync(cursor, 0, (size_t)NBUCK * 4, stream);
    hipLaunchKernelGGL(k_prep_route, dim3(96 + ROUTE_BLKS), dim3(256), 0,
                       stream, W1, W2, w1h, w1l, w2h, w2l, src, dst, cursor,
                       routed);
    hipLaunchKernelGGL(k_bsort_gemm128, dim3(NBUCK + GEMM_BLKS), dim3(256), 0,
                       stream, routed, cursor, counts, start, sorted_src, x,
                       w1h, w1l, h1b);
    hipLaunchKernelGGL(k_agg128_gemm64, dim3(M_TILES), dim3(256), 0, stream,
                       (const unsigned*)h1b, counts, start, sorted_src, b1,
                       w2h, w2l, h2b);
    hipLaunchKernelGGL(k_agg64, dim3(M_TILES), dim3(256), 0, stream,
                       (const unsigned*)h2b, counts, start, sorted_src, b2,
                       (float*)d_out);
  }
}

// Round 7
// 169.982 us; speedup vs baseline: 4.2867x; 2.9129x over previous
//
#include <hip/hip_runtime.h>
#include <hip/hip_fp16.h>
#include <cstddef>
#include <cstdint>

#define N_NODES 50000
#define N_EDGES 600000
#define M_TILES 3125     // 50000 / 16 exactly
#define GEMM_BLKS 782    // ceil(3125/4)
#define NBUCK 196        // ceil(50000/256) coarse buckets (dst>>8)
#define BUCK_CAP 4096    // bucket total ~3072 +- 55
#define ROUTE_EDGES 2048 // edges routed per route block
#define ROUTE_BLKS 293   // ceil(600000/2048)

typedef short bf16x8 __attribute__((ext_vector_type(8)));
typedef float f32x4 __attribute__((ext_vector_type(4)));

// ---------------- bf16 helpers ----------------

__device__ __forceinline__ unsigned short f32_to_bf16(float x) {
  unsigned u = __float_as_uint(x);
  u += 0x7FFFu + ((u >> 16) & 1u);  // round-to-nearest-even
  return (unsigned short)(u >> 16);
}
__device__ __forceinline__ float bf16_to_f32(unsigned short h) {
  return __uint_as_float((unsigned)h << 16);
}
__device__ __forceinline__ float bf16_lo(unsigned g) {
  return __uint_as_float(g << 16);
}
__device__ __forceinline__ float bf16_hi(unsigned g) {
  return __uint_as_float(g & 0xFFFF0000u);
}
// unpack the f16 dinv from a packed (dinv16<<16 | si) word
__device__ __forceinline__ float pk_w(unsigned pk) {
  return __half2float(__ushort_as_half((unsigned short)(pk >> 16)));
}

// Split 8 contiguous fp32 into bf16 hi + bf16 lo fragments (in-register).
__device__ __forceinline__ void split8(const float* __restrict__ p, bf16x8& hi,
                                       bf16x8& lo) {
  const float4 v0 = *(const float4*)p;
  const float4 v1 = *(const float4*)(p + 4);
  float v[8] = {v0.x, v0.y, v0.z, v0.w, v1.x, v1.y, v1.z, v1.w};
#pragma unroll
  for (int i = 0; i < 8; i++) {
    const unsigned short h = f32_to_bf16(v[i]);
    hi[i] = (short)h;
    lo[i] = (short)f32_to_bf16(v[i] - bf16_to_f32(h));
  }
}

// ---------------- MFMA GEMM body: H(bf16) = X[N,128](fp32) @ W[128,COUT] ---
template <int COUT>
__device__ __forceinline__ void gemm_body(const int wtile, const int lane,
                                          const float* __restrict__ X,
                                          const unsigned short* __restrict__ Wph,
                                          const unsigned short* __restrict__ Wpl,
                                          unsigned short* __restrict__ Hs) {
  constexpr int CT = COUT / 16;
  const int m = lane & 15;
  const int q = lane >> 4;

  f32x4 acc[CT];
#pragma unroll
  for (int ct = 0; ct < CT; ct++) acc[ct] = {0.f, 0.f, 0.f, 0.f};

  const float* xp = X + (size_t)(wtile * 16 + m) * 128 + q * 8;

#pragma unroll
  for (int ks = 0; ks < 4; ks++) {
    bf16x8 ah, al;
    split8(xp + ks * 32, ah, al);
#pragma unroll
    for (int ct = 0; ct < CT; ct++) {
      const size_t bo = ((size_t)(ct * 4 + ks) * 64 + lane) * 8;
      const bf16x8 bh = *(const bf16x8*)(Wph + bo);
      const bf16x8 bl = *(const bf16x8*)(Wpl + bo);
      acc[ct] = __builtin_amdgcn_mfma_f32_16x16x32_bf16(ah, bh, acc[ct], 0, 0, 0);
      acc[ct] = __builtin_amdgcn_mfma_f32_16x16x32_bf16(al, bh, acc[ct], 0, 0, 0);
      acc[ct] = __builtin_amdgcn_mfma_f32_16x16x32_bf16(ah, bl, acc[ct], 0, 0, 0);
    }
  }
  // C/D layout: col = lane&15 (=m), row = q*4 + r
#pragma unroll
  for (int ct = 0; ct < CT; ct++) {
#pragma unroll
    for (int r = 0; r < 4; r++) {
      const int orow = wtile * 16 + q * 4 + r;
      Hs[(size_t)orow * COUT + ct * 16 + m] = f32_to_bf16(acc[ct][r]);
    }
  }
}

// ---------------- W-pack body ----------------
__device__ __forceinline__ void wpack_body(const int i,
                                           const float* __restrict__ W1,
                                           const float* __restrict__ W2,
                                           unsigned short* __restrict__ w1h,
                                           unsigned short* __restrict__ w1l,
                                           unsigned short* __restrict__ w2h,
                                           unsigned short* __restrict__ w2l) {
  // Wp[((ct*4+ks)*64+lane)*8+j] = W[(ks*32+(lane>>4)*8+j)*COUT + ct*16+(lane&15)]
  const float* W;
  unsigned short *wh, *wl;
  int o, cout;
  if (i < 16384) {
    W = W1; wh = w1h; wl = w1l; o = i; cout = 128;
  } else {
    W = W2; wh = w2h; wl = w2l; o = i - 16384; cout = 64;
  }
  const int j = o & 7;
  const int ln = (o >> 3) & 63;
  const int t = o >> 9;  // ct*4 + ks
  const int ks = t & 3;
  const int ct = t >> 2;
  const int k = ks * 32 + (ln >> 4) * 8 + j;
  const int n = ct * 16 + (ln & 15);
  const float v = W[k * cout + n];
  const unsigned short h = f32_to_bf16(v);
  wh[o] = h;
  wl[o] = f32_to_bf16(v - bf16_to_f32(h));
}

// ---------------- D1: W-pack || edge routing (+ per-node degree) --------
// blocks [0,96): packw; rest: route edges into coarse buckets AND
// atomicAdd per-edge in-degree into counts[] (zeroed by the memset).
// Global counts before the sort lets D2 pack the source-side norm into
// sorted_src, removing the per-edge counts[si] gather from BOTH agg stages.
// Visibility of counts[]/routed[] to D2 is guaranteed by the dispatch
// boundary (stream order).
__global__ __launch_bounds__(256) void k_prep_route(
    const float* __restrict__ W1, const float* __restrict__ W2,
    unsigned short* __restrict__ w1h, unsigned short* __restrict__ w1l,
    unsigned short* __restrict__ w2h, unsigned short* __restrict__ w2l,
    const int* __restrict__ src, const int* __restrict__ dst,
    int* __restrict__ cursor, int* __restrict__ counts,
    unsigned* __restrict__ routed) {
  __shared__ int hist[NBUCK];
  __shared__ int lcur[NBUCK];
  const int tid = threadIdx.x;
  if (blockIdx.x < 96) {
    wpack_body(blockIdx.x * 256 + tid, W1, W2, w1h, w1l, w2h, w2l);
  } else {
    const int rb = blockIdx.x - 96;
    for (int t = tid; t < NBUCK; t += 256) hist[t] = 0;
    __syncthreads();
    unsigned packed[8];
    bool cvalid[2];
    const int base = rb * ROUTE_EDGES;
#pragma unroll
    for (int c = 0; c < 2; c++) {
      const int i4 = base + c * 1024 + tid * 4;  // always mult of 4
      cvalid[c] = (i4 < N_EDGES);
      if (cvalid[c]) {
        const int4 d4 = *(const int4*)(dst + i4);
        const int4 s4 = *(const int4*)(src + i4);
        packed[c * 4 + 0] = ((unsigned)d4.x << 16) | (unsigned)s4.x;
        packed[c * 4 + 1] = ((unsigned)d4.y << 16) | (unsigned)s4.y;
        packed[c * 4 + 2] = ((unsigned)d4.z << 16) | (unsigned)s4.z;
        packed[c * 4 + 3] = ((unsigned)d4.w << 16) | (unsigned)s4.w;
#pragma unroll
        for (int j = 0; j < 4; j++) {
          const unsigned pk = packed[c * 4 + j];
          atomicAdd(&hist[pk >> 24], 1);       // LDS atomic (bucket hist)
          atomicAdd(&counts[pk >> 16], 1);     // device atomic (in-degree)
        }
      }
    }
    __syncthreads();
    // one device atomic per bucket: claim a contiguous range in the region
    for (int t = tid; t < NBUCK; t += 256)
      lcur[t] = t * BUCK_CAP + atomicAdd(&cursor[t], hist[t]);
    __syncthreads();
#pragma unroll
    for (int c = 0; c < 2; c++) {
      if (cvalid[c]) {
#pragma unroll
        for (int j = 0; j < 4; j++) {
          const unsigned pk = packed[c * 4 + j];
          const int slot = atomicAdd(&lcur[pk >> 24], 1);  // LDS atomic
          routed[slot] = pk;
        }
      }
    }
  }
}

// ---------------- D2: per-bucket counting sort || layer-1 GEMM ----------
// Sort now also packs f16(rsqrt(counts[si]+1)) into the high half of each
// sorted_src entry — one counts[si] gather per edge HERE (hidden under the
// co-dispatched GEMM1) instead of one per edge per agg stage (2x) later.
__global__ __launch_bounds__(256) void k_bsort_gemm128(
    const unsigned* __restrict__ routed, const int* __restrict__ cursor,
    const int* __restrict__ counts, int* __restrict__ start,
    int* __restrict__ sorted_src, const float* __restrict__ X,
    const unsigned short* __restrict__ Wph,
    const unsigned short* __restrict__ Wpl, unsigned short* __restrict__ Hs) {
  __shared__ unsigned ebuf[BUCK_CAP];
  __shared__ int h2[256];
  __shared__ int c2[256];
  const int tid = threadIdx.x;
  if (blockIdx.x < NBUCK) {
    const int b = blockIdx.x;
    const int n = cursor[b];  // count-based
    for (int i = tid; i < n; i += 256) ebuf[i] = routed[b * BUCK_CAP + i];
    h2[tid] = 0;
    __syncthreads();
    for (int i = tid; i < n; i += 256)
      atomicAdd(&h2[(ebuf[i] >> 16) & 255], 1);
    __syncthreads();
    const int own = h2[tid];
    for (int s = 1; s < 256; s <<= 1) {
      const int t = (tid >= s) ? h2[tid - s] : 0;
      __syncthreads();
      h2[tid] += t;
      __syncthreads();
    }
    const int pfx = h2[tid] - own;  // exclusive prefix
    c2[tid] = pfx;
    const int d = b * 256 + tid;
    if (d < N_NODES) start[d] = b * BUCK_CAP + pfx;
    __syncthreads();
    for (int i = tid; i < n; i += 256) {
      const unsigned pk = ebuf[i];
      const int r = atomicAdd(&c2[(pk >> 16) & 255], 1);  // LDS atomic
      const unsigned si = pk & 0xFFFFu;
      const float rs = rsqrtf((float)counts[si] + 1.0f);
      const unsigned hb = (unsigned)__half_as_ushort(__float2half(rs));
      sorted_src[b * BUCK_CAP + r] = (int)(si | (hb << 16));
    }
  } else {
    const int wtile = (blockIdx.x - NBUCK) * 4 + (tid >> 6);
    if (wtile < M_TILES) gemm_body<128>(wtile, tid & 63, X, Wph, Wpl, Hs);
  }
}

// ---------------- D3: fused layer-1 aggregation + layer-2 GEMM ----------
// Half-wave (32 lanes x uint2 = full 256 B row) per node. Metadata for
// BOTH node pairs hoisted (round-1 version serialized the p=1 chain).
// Per edge: ONE shuffle of the packed (dinv16|si) word — no counts[si]
// load, no second shuffle. Accumulation order per feature unchanged
// (self, edges ascending, bias); weights carry f16-quantized dinv.
__global__ __launch_bounds__(256) void k_agg128_gemm64(
    const unsigned* __restrict__ Hb, const int* __restrict__ counts,
    const int* __restrict__ start, const int* __restrict__ sorted_src,
    const float* __restrict__ bias, const unsigned short* __restrict__ Wph,
    const unsigned short* __restrict__ Wpl, unsigned short* __restrict__ Hs) {
  __shared__ float a1s[16][132];  // +4 pad: A-read bank aliasing 16->8 way
  const int lane = threadIdx.x & 63;
  const int wave = threadIdx.x >> 6;
  const int h = lane >> 5;  // half id: which node of the pair
  const int c = lane & 31;  // uint2 column within the 256 B row
  const uint2* __restrict__ Hb2 = (const uint2*)Hb;
  const float4 bb = ((const float4*)bias)[c];
  const int vbase = blockIdx.x * 16 + wave * 4;

  // hoisted metadata for both pairs (p=0: nodes vbase+h, p=1: vbase+2+h)
  const int v0 = vbase + h, v1 = vbase + 2 + h;
  const int deg0 = counts[v0], deg1 = counts[v1];
  const int e00 = start[v0], e01 = start[v1];
  const float dv0 = rsqrtf((float)deg0 + 1.f);
  const float dv1 = rsqrtf((float)deg1 + 1.f);
  const uint2 gs0 = Hb2[(size_t)v0 * 32 + c];
  const uint2 gs1 = Hb2[(size_t)v1 * 32 + c];
  const int pk0 = (c < deg0) ? sorted_src[e00 + c] : 0;  // w=0 when invalid
  const int pk1 = (c < deg1) ? sorted_src[e01 + c] : 0;

#pragma unroll
  for (int p = 0; p < 2; p++) {
    const int deg = p ? deg1 : deg0;
    const int e0 = p ? e01 : e00;
    const float dv = p ? dv1 : dv0;
    const uint2 gs = p ? gs1 : gs0;
    const int pk = p ? pk1 : pk0;

    const int dA = __shfl(deg, 0);
    const int dB = __shfl(deg, 32);
    const int mm = max(dA, dB);
    const int m = min(mm, 32);
    const float dv2 = dv * dv;
    float a0 = bf16_lo(gs.x) * dv2;
    float a1 = bf16_hi(gs.x) * dv2;
    float a2 = bf16_lo(gs.y) * dv2;
    float a3 = bf16_hi(gs.y) * dv2;

    for (int j = 0; j < m; j += 8) {
      unsigned pkt[8];
      float w[8];
      uint2 g[8];
#pragma unroll
      for (int t = 0; t < 8; t++)
        pkt[t] = (unsigned)__shfl(pk, (lane & 32) | (j + t));
#pragma unroll
      for (int t = 0; t < 8; t++)
        g[t] = Hb2[(size_t)(pkt[t] & 0xFFFFu) * 32 + c];
#pragma unroll
      for (int t = 0; t < 8; t++) w[t] = pk_w(pkt[t]) * dv;
#pragma unroll
      for (int t = 0; t < 8; t++) {
        a0 += bf16_lo(g[t].x) * w[t];
        a1 += bf16_hi(g[t].x) * w[t];
        a2 += bf16_lo(g[t].y) * w[t];
        a3 += bf16_hi(g[t].y) * w[t];
      }
    }
    // rare tail: deg > 32 (max in-degree ~35 for this input)
    for (int base = 32; base < mm; base += 32) {
      int pk2 = 0;
      if (base + c < deg) pk2 = sorted_src[e0 + base + c];
      const int lim = min(32, mm - base);
      for (int k = 0; k < lim; k++) {
        const unsigned pt = (unsigned)__shfl(pk2, (lane & 32) | k);
        const uint2 g = Hb2[(size_t)(pt & 0xFFFFu) * 32 + c];
        const float w = pk_w(pt) * dv;
        a0 += bf16_lo(g.x) * w;
        a1 += bf16_hi(g.x) * w;
        a2 += bf16_lo(g.y) * w;
        a3 += bf16_hi(g.y) * w;
      }
    }
    float4 r;
    r.x = fmaxf(a0 + bb.x, 0.f);
    r.y = fmaxf(a1 + bb.y, 0.f);
    r.z = fmaxf(a2 + bb.z, 0.f);
    r.w = fmaxf(a3 + bb.w, 0.f);
    *(float4*)&a1s[wave * 4 + 2 * p + h][c * 4] = r;  // 528 B rows
  }
  __syncthreads();

  // GEMM2: each wave computes one 16x16 column tile of h2 = a1 @ W2
  const int ct = wave;
  const int m2 = lane & 15;
  const int q = lane >> 4;
  f32x4 acc = {0.f, 0.f, 0.f, 0.f};
#pragma unroll
  for (int ks = 0; ks < 4; ks++) {
    bf16x8 ah, al;
    split8(&a1s[m2][ks * 32 + q * 8], ah, al);
    const size_t bo = ((size_t)(ct * 4 + ks) * 64 + lane) * 8;
    const bf16x8 bh = *(const bf16x8*)(Wph + bo);
    const bf16x8 bl = *(const bf16x8*)(Wpl + bo);
    acc = __builtin_amdgcn_mfma_f32_16x16x32_bf16(ah, bh, acc, 0, 0, 0);
    acc = __builtin_amdgcn_mfma_f32_16x16x32_bf16(al, bh, acc, 0, 0, 0);
    acc = __builtin_amdgcn_mfma_f32_16x16x32_bf16(ah, bl, acc, 0, 0, 0);
  }
#pragma unroll
  for (int r = 0; r < 4; r++) {
    const int orow = blockIdx.x * 16 + q * 4 + r;
    Hs[(size_t)orow * 64 + ct * 16 + m2] = f32_to_bf16(acc[r]);
  }
}

// ---------------- D4: layer-2 aggregation (COUT=64, no relu) ------------
// Quarter-wave (16 lanes x uint2 = full 128 B row) per node. One packed
// shuffle per edge; no counts[si] loads.
__global__ __launch_bounds__(256) void k_agg64(
    const unsigned* __restrict__ Hb, const int* __restrict__ counts,
    const int* __restrict__ start, const int* __restrict__ sorted_src,
    const float* __restrict__ bias, float* __restrict__ out) {
  const int lane = threadIdx.x & 63;
  const int wave = threadIdx.x >> 6;
  const int qq = lane >> 4;  // quarter id: which node
  const int c = lane & 15;   // uint2 column within the 128 B row
  const uint2* __restrict__ Hb2 = (const uint2*)Hb;
  const float4 bb = ((const float4*)bias)[c];

  const int v = blockIdx.x * 16 + wave * 4 + qq;
  const int deg = counts[v];
  const int e0 = start[v];
  const float dv = rsqrtf((float)deg + 1.0f);
  const uint2 gs = Hb2[(size_t)v * 16 + c];
  const int pk0 = (c < deg) ? sorted_src[e0 + c] : 0;
  const int pk1 = (c + 16 < deg) ? sorted_src[e0 + c + 16] : 0;

  const int d0 = __shfl(deg, 0);
  const int d1 = __shfl(deg, 16);
  const int d2 = __shfl(deg, 32);
  const int d3 = __shfl(deg, 48);
  const int mm = max(max(d0, d1), max(d2, d3));
  const int m = min(mm, 32);
  const float dv2 = dv * dv;
  float a0 = bf16_lo(gs.x) * dv2;
  float a1 = bf16_hi(gs.x) * dv2;
  float a2 = bf16_lo(gs.y) * dv2;
  float a3 = bf16_hi(gs.y) * dv2;

#pragma unroll
  for (int jb = 0; jb < 4; jb++) {
    if (jb * 8 < m) {
      unsigned pkt[8];
      float w[8];
      uint2 g[8];
#pragma unroll
      for (int t = 0; t < 8; t++) {
        const int e = jb * 8 + t;  // 0..31
        const int srcl = (lane & 48) | (e & 15);
        pkt[t] = (unsigned)__shfl((jb < 2) ? pk0 : pk1, srcl);
      }
#pragma unroll
      for (int t = 0; t < 8; t++)
        g[t] = Hb2[(size_t)(pkt[t] & 0xFFFFu) * 16 + c];
#pragma unroll
      for (int t = 0; t < 8; t++) w[t] = pk_w(pkt[t]) * dv;
#pragma unroll
      for (int t = 0; t < 8; t++) {
        a0 += bf16_lo(g[t].x) * w[t];
        a1 += bf16_hi(g[t].x) * w[t];
        a2 += bf16_lo(g[t].y) * w[t];
        a3 += bf16_hi(g[t].y) * w[t];
      }
    }
  }
  // rare tail: deg > 32
  for (int base = 32; base < mm; base += 16) {
    int pk2 = 0;
    if (base + c < deg) pk2 = sorted_src[e0 + base + c];
    const int lim = min(16, mm - base);
    for (int k = 0; k < lim; k++) {
      const unsigned pt = (unsigned)__shfl(pk2, (lane & 48) | k);
      const uint2 g = Hb2[(size_t)(pt & 0xFFFFu) * 16 + c];
      const float w = pk_w(pt) * dv;
      a0 += bf16_lo(g.x) * w;
      a1 += bf16_hi(g.x) * w;
      a2 += bf16_lo(g.y) * w;
      a3 += bf16_hi(g.y) * w;
    }
  }
  float4 r;
  r.x = a0 + bb.x;
  r.y = a1 + bb.y;
  r.z = a2 + bb.z;
  r.w = a3 + bb.w;
  ((float4*)out)[(size_t)v * 16 + c] = r;
}

// ---------------- launch ----------------

extern "C" void kernel_launch(void* const* d_in, const int* in_sizes, int n_in,
                              void* d_out, int out_size, void* d_ws, size_t ws_size,
                              hipStream_t stream) {
  const float* x = (const float*)d_in[0];
  const int* ei = (const int*)d_in[1];
  const float* W1 = (const float*)d_in[2];
  const float* b1 = (const float*)d_in[3];
  const float* W2 = (const float*)d_in[4];
  const float* b2 = (const float*)d_in[5];
  const int* src = ei;
  const int* dst = ei + N_EDGES;

  char* p = (char*)d_ws;
  auto alloc = [&](size_t bytes) {
    char* q = p;
    p += (bytes + 255) & ~(size_t)255;
    return q;
  };
  // cursor + counts contiguous -> single zeroing memset
  int* cursor = (int*)alloc((size_t)NBUCK * 4);
  int* counts = (int*)alloc((size_t)N_NODES * 4);
  unsigned* routed = (unsigned*)alloc((size_t)NBUCK * BUCK_CAP * 4);
  int* sorted_src = (int*)alloc((size_t)NBUCK * BUCK_CAP * 4);
  int* start = (int*)alloc((size_t)N_NODES * 4);
  unsigned short* w1h = (unsigned short*)alloc(16384 * 2);
  unsigned short* w1l = (unsigned short*)alloc(16384 * 2);
  unsigned short* w2h = (unsigned short*)alloc(8192 * 2);
  unsigned short* w2l = (unsigned short*)alloc(8192 * 2);
  unsigned short* h1b = (unsigned short*)alloc((size_t)N_NODES * 128 * 2);
  unsigned short* h2b = (unsigned short*)alloc((size_t)N_NODES * 64 * 2);

  const size_t zlen = (size_t)((char*)counts - (char*)cursor) + (size_t)N_NODES * 4;
  hipMemsetAsync(cursor, 0, zlen, stream);
  hipLaunchKernelGGL(k_prep_route, dim3(96 + ROUTE_BLKS), dim3(256), 0, stream,
                     W1, W2, w1h, w1l, w2h, w2l, src, dst, cursor, counts,
                     routed);
  hipLaunchKernelGGL(k_bsort_gemm128, dim3(NBUCK + GEMM_BLKS), dim3(256), 0,
                     stream, routed, cursor, counts, start, sorted_src, x, w1h,
                     w1l, h1b);
  hipLaunchKernelGGL(k_agg128_gemm64, dim3(M_TILES), dim3(256), 0, stream,
                     (const unsigned*)h1b, counts, start, sorted_src, b1, w2h,
                     w2l, h2b);
  hipLaunchKernelGGL(k_agg64, dim3(M_TILES), dim3(256), 0, stream,
                     (const unsigned*)h2b, counts, start, sorted_src, b2,
                     (float*)d_out);
}

// Round 8
// 146.904 us; speedup vs baseline: 4.9601x; 1.1571x over previous
//
#include <hip/hip_runtime.h>
#include <hip/hip_fp16.h>
#include <cstddef>
#include <cstdint>

#define N_NODES 50000
#define N_EDGES 600000
#define M_TILES 3125     // 50000 / 16 exactly
#define GEMM_BLKS 782    // ceil(3125/4)
#define NBUCK 196        // ceil(50000/256) coarse buckets (dst>>8)
#define BUCK_CAP 4096    // bucket total ~3072 +- 55
#define ROUTE_EDGES 2048 // edges routed per route block
#define ROUTE_BLKS 293   // ceil(600000/2048)

typedef short bf16x8 __attribute__((ext_vector_type(8)));
typedef float f32x4 __attribute__((ext_vector_type(4)));

// ---------------- bf16 helpers ----------------

__device__ __forceinline__ unsigned short f32_to_bf16(float x) {
  unsigned u = __float_as_uint(x);
  u += 0x7FFFu + ((u >> 16) & 1u);  // round-to-nearest-even
  return (unsigned short)(u >> 16);
}
__device__ __forceinline__ float bf16_to_f32(unsigned short h) {
  return __uint_as_float((unsigned)h << 16);
}
__device__ __forceinline__ float bf16_lo(unsigned g) {
  return __uint_as_float(g << 16);
}
__device__ __forceinline__ float bf16_hi(unsigned g) {
  return __uint_as_float(g & 0xFFFF0000u);
}
// unpack the f16 dinv from a packed (dinv16<<16 | si) word
__device__ __forceinline__ float pk_w(unsigned pk) {
  return __half2float(__ushort_as_half((unsigned short)(pk >> 16)));
}
__device__ __forceinline__ int pack_si(int si, float dinv) {
  return si | ((int)__half_as_ushort(__float2half(dinv)) << 16);
}

// Split 8 contiguous fp32 into bf16 hi + bf16 lo fragments (in-register).
__device__ __forceinline__ void split8(const float* __restrict__ p, bf16x8& hi,
                                       bf16x8& lo) {
  const float4 v0 = *(const float4*)p;
  const float4 v1 = *(const float4*)(p + 4);
  float v[8] = {v0.x, v0.y, v0.z, v0.w, v1.x, v1.y, v1.z, v1.w};
#pragma unroll
  for (int i = 0; i < 8; i++) {
    const unsigned short h = f32_to_bf16(v[i]);
    hi[i] = (short)h;
    lo[i] = (short)f32_to_bf16(v[i] - bf16_to_f32(h));
  }
}

// ---------------- MFMA GEMM body: H(bf16) = X[N,128](fp32) @ W[128,COUT] ---
template <int COUT>
__device__ __forceinline__ void gemm_body(const int wtile, const int lane,
                                          const float* __restrict__ X,
                                          const unsigned short* __restrict__ Wph,
                                          const unsigned short* __restrict__ Wpl,
                                          unsigned short* __restrict__ Hs) {
  constexpr int CT = COUT / 16;
  const int m = lane & 15;
  const int q = lane >> 4;

  f32x4 acc[CT];
#pragma unroll
  for (int ct = 0; ct < CT; ct++) acc[ct] = {0.f, 0.f, 0.f, 0.f};

  const float* xp = X + (size_t)(wtile * 16 + m) * 128 + q * 8;

#pragma unroll
  for (int ks = 0; ks < 4; ks++) {
    bf16x8 ah, al;
    split8(xp + ks * 32, ah, al);
#pragma unroll
    for (int ct = 0; ct < CT; ct++) {
      const size_t bo = ((size_t)(ct * 4 + ks) * 64 + lane) * 8;
      const bf16x8 bh = *(const bf16x8*)(Wph + bo);
      const bf16x8 bl = *(const bf16x8*)(Wpl + bo);
      acc[ct] = __builtin_amdgcn_mfma_f32_16x16x32_bf16(ah, bh, acc[ct], 0, 0, 0);
      acc[ct] = __builtin_amdgcn_mfma_f32_16x16x32_bf16(al, bh, acc[ct], 0, 0, 0);
      acc[ct] = __builtin_amdgcn_mfma_f32_16x16x32_bf16(ah, bl, acc[ct], 0, 0, 0);
    }
  }
  // C/D layout: col = lane&15 (=m), row = q*4 + r
#pragma unroll
  for (int ct = 0; ct < CT; ct++) {
#pragma unroll
    for (int r = 0; r < 4; r++) {
      const int orow = wtile * 16 + q * 4 + r;
      Hs[(size_t)orow * COUT + ct * 16 + m] = f32_to_bf16(acc[ct][r]);
    }
  }
}

// ---------------- W-pack body ----------------
__device__ __forceinline__ void wpack_body(const int i,
                                           const float* __restrict__ W1,
                                           const float* __restrict__ W2,
                                           unsigned short* __restrict__ w1h,
                                           unsigned short* __restrict__ w1l,
                                           unsigned short* __restrict__ w2h,
                                           unsigned short* __restrict__ w2l) {
  // Wp[((ct*4+ks)*64+lane)*8+j] = W[(ks*32+(lane>>4)*8+j)*COUT + ct*16+(lane&15)]
  const float* W;
  unsigned short *wh, *wl;
  int o, cout;
  if (i < 16384) {
    W = W1; wh = w1h; wl = w1l; o = i; cout = 128;
  } else {
    W = W2; wh = w2h; wl = w2l; o = i - 16384; cout = 64;
  }
  const int j = o & 7;
  const int ln = (o >> 3) & 63;
  const int t = o >> 9;  // ct*4 + ks
  const int ks = t & 3;
  const int ct = t >> 2;
  const int k = ks * 32 + (ln >> 4) * 8 + j;
  const int n = ct * 16 + (ln & 15);
  const float v = W[k * cout + n];
  const unsigned short h = f32_to_bf16(v);
  wh[o] = h;
  wl[o] = f32_to_bf16(v - bf16_to_f32(h));
}

// ---------------- D1: W-pack || edge routing (R1-verified form) ---------
// blocks [0,96): packw; rest: route edges into coarse buckets (LDS
// histogram, one range-claim atomic per bucket per block, LDS-cursor
// scatter of packed (dst<<16)|src words). NO per-edge device atomics —
// degree comes free from D2's sort histogram (R7's counts atomics cost
// +17 us net).
__global__ __launch_bounds__(256) void k_prep_route(
    const float* __restrict__ W1, const float* __restrict__ W2,
    unsigned short* __restrict__ w1h, unsigned short* __restrict__ w1l,
    unsigned short* __restrict__ w2h, unsigned short* __restrict__ w2l,
    const int* __restrict__ src, const int* __restrict__ dst,
    int* __restrict__ cursor, unsigned* __restrict__ routed) {
  __shared__ int hist[NBUCK];
  __shared__ int lcur[NBUCK];
  const int tid = threadIdx.x;
  if (blockIdx.x < 96) {
    wpack_body(blockIdx.x * 256 + tid, W1, W2, w1h, w1l, w2h, w2l);
  } else {
    const int rb = blockIdx.x - 96;
    for (int t = tid; t < NBUCK; t += 256) hist[t] = 0;
    __syncthreads();
    unsigned packed[8];
    bool cvalid[2];
    const int base = rb * ROUTE_EDGES;
#pragma unroll
    for (int c = 0; c < 2; c++) {
      const int i4 = base + c * 1024 + tid * 4;  // always mult of 4
      cvalid[c] = (i4 < N_EDGES);
      if (cvalid[c]) {
        const int4 d4 = *(const int4*)(dst + i4);
        const int4 s4 = *(const int4*)(src + i4);
        packed[c * 4 + 0] = ((unsigned)d4.x << 16) | (unsigned)s4.x;
        packed[c * 4 + 1] = ((unsigned)d4.y << 16) | (unsigned)s4.y;
        packed[c * 4 + 2] = ((unsigned)d4.z << 16) | (unsigned)s4.z;
        packed[c * 4 + 3] = ((unsigned)d4.w << 16) | (unsigned)s4.w;
#pragma unroll
        for (int j = 0; j < 4; j++)
          atomicAdd(&hist[packed[c * 4 + j] >> 24], 1);  // LDS atomic
      }
    }
    __syncthreads();
    // one device atomic per bucket: claim a contiguous range in the region
    for (int t = tid; t < NBUCK; t += 256)
      lcur[t] = t * BUCK_CAP + atomicAdd(&cursor[t], hist[t]);
    __syncthreads();
#pragma unroll
    for (int c = 0; c < 2; c++) {
      if (cvalid[c]) {
#pragma unroll
        for (int j = 0; j < 4; j++) {
          const unsigned pk = packed[c * 4 + j];
          const int slot = atomicAdd(&lcur[pk >> 24], 1);  // LDS atomic
          routed[slot] = pk;
        }
      }
    }
  }
}

// ---------------- D2: per-bucket counting sort || layer-1 GEMM ----------
// R1-verified form: counts[d] = own (free from histogram); sorted_src
// entries are plain src ids.
__global__ __launch_bounds__(256) void k_bsort_gemm128(
    const unsigned* __restrict__ routed, const int* __restrict__ cursor,
    int* __restrict__ counts, int* __restrict__ start,
    int* __restrict__ sorted_src, const float* __restrict__ X,
    const unsigned short* __restrict__ Wph,
    const unsigned short* __restrict__ Wpl, unsigned short* __restrict__ Hs) {
  __shared__ unsigned ebuf[BUCK_CAP];
  __shared__ int h2[256];
  __shared__ int c2[256];
  const int tid = threadIdx.x;
  if (blockIdx.x < NBUCK) {
    const int b = blockIdx.x;
    const int n = cursor[b];  // count-based
    for (int i = tid; i < n; i += 256) ebuf[i] = routed[b * BUCK_CAP + i];
    h2[tid] = 0;
    __syncthreads();
    for (int i = tid; i < n; i += 256)
      atomicAdd(&h2[(ebuf[i] >> 16) & 255], 1);
    __syncthreads();
    const int own = h2[tid];
    for (int s = 1; s < 256; s <<= 1) {
      const int t = (tid >= s) ? h2[tid - s] : 0;
      __syncthreads();
      h2[tid] += t;
      __syncthreads();
    }
    const int pfx = h2[tid] - own;  // exclusive prefix
    c2[tid] = pfx;
    const int d = b * 256 + tid;
    if (d < N_NODES) {
      counts[d] = own;
      start[d] = b * BUCK_CAP + pfx;
    }
    __syncthreads();
    for (int i = tid; i < n; i += 256) {
      const unsigned pk = ebuf[i];
      const int r = atomicAdd(&c2[(pk >> 16) & 255], 1);  // LDS atomic
      sorted_src[b * BUCK_CAP + r] = (int)(pk & 0xFFFFu);
    }
  } else {
    const int wtile = (blockIdx.x - NBUCK) * 4 + (tid >> 6);
    if (wtile < M_TILES) gemm_body<128>(wtile, tid & 63, X, Wph, Wpl, Hs);
  }
}

// ---------------- D3: fused layer-1 aggregation + layer-2 GEMM ----------
// Half-wave (32 lanes x uint2 = full 256 B row) per node. Metadata for
// both node pairs hoisted. D3 gathers counts[si] anyway (exact fp32
// weights, numerics == R1); it writes the packed (f16(dinv)<<16 | si)
// BACK into sorted_src for D4 — each slot read+written by the same
// thread, so no race; dispatch boundary orders it for D4.
__global__ __launch_bounds__(256) void k_agg128_gemm64(
    const unsigned* __restrict__ Hb, const int* __restrict__ counts,
    const int* __restrict__ start, int* __restrict__ sorted_src,
    const float* __restrict__ bias, const unsigned short* __restrict__ Wph,
    const unsigned short* __restrict__ Wpl, unsigned short* __restrict__ Hs) {
  __shared__ float a1s[16][132];  // +4 pad: A-read bank aliasing 16->8 way
  const int lane = threadIdx.x & 63;
  const int wave = threadIdx.x >> 6;
  const int h = lane >> 5;  // half id: which node of the pair
  const int c = lane & 31;  // uint2 column within the 256 B row
  const uint2* __restrict__ Hb2 = (const uint2*)Hb;
  const float4 bb = ((const float4*)bias)[c];
  const int vbase = blockIdx.x * 16 + wave * 4;

  // hoisted metadata for both pairs (p=0: nodes vbase+h, p=1: vbase+2+h)
  const int v0 = vbase + h, v1 = vbase + 2 + h;
  const int deg0 = counts[v0], deg1 = counts[v1];
  const int e00 = start[v0], e01 = start[v1];
  const float dv0 = rsqrtf((float)deg0 + 1.f);
  const float dv1 = rsqrtf((float)deg1 + 1.f);
  const uint2 gs0 = Hb2[(size_t)v0 * 32 + c];
  const uint2 gs1 = Hb2[(size_t)v1 * 32 + c];
  int si0 = 0, si1 = 0;
  float di0 = 0.f, di1 = 0.f;  // exact fp32 source-side dinv
  if (c < deg0) {
    si0 = sorted_src[e00 + c];
    di0 = rsqrtf((float)counts[si0] + 1.f);
  }
  if (c < deg1) {
    si1 = sorted_src[e01 + c];
    di1 = rsqrtf((float)counts[si1] + 1.f);
  }
  // pack-back for D4 (coalesced streamed stores; same-thread slots)
  if (c < deg0) sorted_src[e00 + c] = pack_si(si0, di0);
  if (c < deg1) sorted_src[e01 + c] = pack_si(si1, di1);

#pragma unroll
  for (int p = 0; p < 2; p++) {
    const int deg = p ? deg1 : deg0;
    const int e0 = p ? e01 : e00;
    const float dv = p ? dv1 : dv0;
    const uint2 gs = p ? gs1 : gs0;
    const int si = p ? si1 : si0;
    const float wi = (p ? di1 : di0) * dv;

    const int dA = __shfl(deg, 0);
    const int dB = __shfl(deg, 32);
    const int mm = max(dA, dB);
    const int m = min(mm, 32);
    const float dv2 = dv * dv;
    float a0 = bf16_lo(gs.x) * dv2;
    float a1 = bf16_hi(gs.x) * dv2;
    float a2 = bf16_lo(gs.y) * dv2;
    float a3 = bf16_hi(gs.y) * dv2;

    for (int j = 0; j < m; j += 8) {
      int s[8];
      float w[8];
      uint2 g[8];
#pragma unroll
      for (int t = 0; t < 8; t++) {
        s[t] = __shfl(si, (lane & 32) | (j + t));
        w[t] = __shfl(wi, (lane & 32) | (j + t));
      }
#pragma unroll
      for (int t = 0; t < 8; t++) g[t] = Hb2[(size_t)s[t] * 32 + c];
#pragma unroll
      for (int t = 0; t < 8; t++) {
        a0 += bf16_lo(g[t].x) * w[t];
        a1 += bf16_hi(g[t].x) * w[t];
        a2 += bf16_lo(g[t].y) * w[t];
        a3 += bf16_hi(g[t].y) * w[t];
      }
    }
    // rare tail: deg > 32 (max in-degree ~35 for this input)
    for (int base = 32; base < mm; base += 32) {
      int sit = 0;
      float dit = 0.f;
      if (base + c < deg) {
        sit = sorted_src[e0 + base + c];
        dit = rsqrtf((float)counts[sit] + 1.0f);
        sorted_src[e0 + base + c] = pack_si(sit, dit);  // pack-back (tail)
      }
      const float wit = dit * dv;
      const int lim = min(32, mm - base);
      for (int k = 0; k < lim; k++) {
        const int s = __shfl(sit, (lane & 32) | k);
        const float w = __shfl(wit, (lane & 32) | k);
        const uint2 g = Hb2[(size_t)s * 32 + c];
        a0 += bf16_lo(g.x) * w;
        a1 += bf16_hi(g.x) * w;
        a2 += bf16_lo(g.y) * w;
        a3 += bf16_hi(g.y) * w;
      }
    }
    float4 r;
    r.x = fmaxf(a0 + bb.x, 0.f);
    r.y = fmaxf(a1 + bb.y, 0.f);
    r.z = fmaxf(a2 + bb.z, 0.f);
    r.w = fmaxf(a3 + bb.w, 0.f);
    *(float4*)&a1s[wave * 4 + 2 * p + h][c * 4] = r;  // 528 B rows
  }
  __syncthreads();

  // GEMM2: each wave computes one 16x16 column tile of h2 = a1 @ W2
  const int ct = wave;
  const int m2 = lane & 15;
  const int q = lane >> 4;
  f32x4 acc = {0.f, 0.f, 0.f, 0.f};
#pragma unroll
  for (int ks = 0; ks < 4; ks++) {
    bf16x8 ah, al;
    split8(&a1s[m2][ks * 32 + q * 8], ah, al);
    const size_t bo = ((size_t)(ct * 4 + ks) * 64 + lane) * 8;
    const bf16x8 bh = *(const bf16x8*)(Wph + bo);
    const bf16x8 bl = *(const bf16x8*)(Wpl + bo);
    acc = __builtin_amdgcn_mfma_f32_16x16x32_bf16(ah, bh, acc, 0, 0, 0);
    acc = __builtin_amdgcn_mfma_f32_16x16x32_bf16(al, bh, acc, 0, 0, 0);
    acc = __builtin_amdgcn_mfma_f32_16x16x32_bf16(ah, bl, acc, 0, 0, 0);
  }
#pragma unroll
  for (int r = 0; r < 4; r++) {
    const int orow = blockIdx.x * 16 + q * 4 + r;
    Hs[(size_t)orow * 64 + ct * 16 + m2] = f32_to_bf16(acc[r]);
  }
}

// ---------------- D4: layer-2 aggregation (COUT=64, no relu) ------------
// Quarter-wave (16 lanes x uint2 = full 128 B row) per node. Consumes the
// packed (dinv16|si) sorted_src from D3: no counts[si] gathers, one
// shuffle per edge instead of two, shorter preload chain.
__global__ __launch_bounds__(256) void k_agg64(
    const unsigned* __restrict__ Hb, const int* __restrict__ counts,
    const int* __restrict__ start, const int* __restrict__ sorted_src,
    const float* __restrict__ bias, float* __restrict__ out) {
  const int lane = threadIdx.x & 63;
  const int wave = threadIdx.x >> 6;
  const int qq = lane >> 4;  // quarter id: which node
  const int c = lane & 15;   // uint2 column within the 128 B row
  const uint2* __restrict__ Hb2 = (const uint2*)Hb;
  const float4 bb = ((const float4*)bias)[c];

  const int v = blockIdx.x * 16 + wave * 4 + qq;
  const int deg = counts[v];
  const int e0 = start[v];
  const float dv = rsqrtf((float)deg + 1.0f);
  const uint2 gs = Hb2[(size_t)v * 16 + c];
  const int pk0 = (c < deg) ? sorted_src[e0 + c] : 0;          // pk_w(0)=0
  const int pk1 = (c + 16 < deg) ? sorted_src[e0 + c + 16] : 0;

  const int d0 = __shfl(deg, 0);
  const int d1 = __shfl(deg, 16);
  const int d2 = __shfl(deg, 32);
  const int d3 = __shfl(deg, 48);
  const int mm = max(max(d0, d1), max(d2, d3));
  const int m = min(mm, 32);
  const float dv2 = dv * dv;
  float a0 = bf16_lo(gs.x) * dv2;
  float a1 = bf16_hi(gs.x) * dv2;
  float a2 = bf16_lo(gs.y) * dv2;
  float a3 = bf16_hi(gs.y) * dv2;

#pragma unroll
  for (int jb = 0; jb < 4; jb++) {
    if (jb * 8 < m) {
      unsigned pkt[8];
      float w[8];
      uint2 g[8];
#pragma unroll
      for (int t = 0; t < 8; t++) {
        const int e = jb * 8 + t;  // 0..31
        const int srcl = (lane & 48) | (e & 15);
        pkt[t] = (unsigned)__shfl((jb < 2) ? pk0 : pk1, srcl);
      }
#pragma unroll
      for (int t = 0; t < 8; t++)
        g[t] = Hb2[(size_t)(pkt[t] & 0xFFFFu) * 16 + c];
#pragma unroll
      for (int t = 0; t < 8; t++) w[t] = pk_w(pkt[t]) * dv;
#pragma unroll
      for (int t = 0; t < 8; t++) {
        a0 += bf16_lo(g[t].x) * w[t];
        a1 += bf16_hi(g[t].x) * w[t];
        a2 += bf16_lo(g[t].y) * w[t];
        a3 += bf16_hi(g[t].y) * w[t];
      }
    }
  }
  // rare tail: deg > 32
  for (int base = 32; base < mm; base += 16) {
    int pk2 = 0;
    if (base + c < deg) pk2 = sorted_src[e0 + base + c];
    const int lim = min(16, mm - base);
    for (int k = 0; k < lim; k++) {
      const unsigned pt = (unsigned)__shfl(pk2, (lane & 48) | k);
      const uint2 g = Hb2[(size_t)(pt & 0xFFFFu) * 16 + c];
      const float w = pk_w(pt) * dv;
      a0 += bf16_lo(g.x) * w;
      a1 += bf16_hi(g.x) * w;
      a2 += bf16_lo(g.y) * w;
      a3 += bf16_hi(g.y) * w;
    }
  }
  float4 r;
  r.x = a0 + bb.x;
  r.y = a1 + bb.y;
  r.z = a2 + bb.z;
  r.w = a3 + bb.w;
  ((float4*)out)[(size_t)v * 16 + c] = r;
}

// ---------------- launch ----------------

extern "C" void kernel_launch(void* const* d_in, const int* in_sizes, int n_in,
                              void* d_out, int out_size, void* d_ws, size_t ws_size,
                              hipStream_t stream) {
  const float* x = (const float*)d_in[0];
  const int* ei = (const int*)d_in[1];
  const float* W1 = (const float*)d_in[2];
  const float* b1 = (const float*)d_in[3];
  const float* W2 = (const float*)d_in[4];
  const float* b2 = (const float*)d_in[5];
  const int* src = ei;
  const int* dst = ei + N_EDGES;

  char* p = (char*)d_ws;
  auto alloc = [&](size_t bytes) {
    char* q = p;
    p += (bytes + 255) & ~(size_t)255;
    return q;
  };
  int* cursor = (int*)alloc((size_t)NBUCK * 4);
  unsigned* routed = (unsigned*)alloc((size_t)NBUCK * BUCK_CAP * 4);
  int* sorted_src = (int*)alloc((size_t)NBUCK * BUCK_CAP * 4);
  int* counts = (int*)alloc((size_t)N_NODES * 4);
  int* start = (int*)alloc((size_t)N_NODES * 4);
  unsigned short* w1h = (unsigned short*)alloc(16384 * 2);
  unsigned short* w1l = (unsigned short*)alloc(16384 * 2);
  unsigned short* w2h = (unsigned short*)alloc(8192 * 2);
  unsigned short* w2l = (unsigned short*)alloc(8192 * 2);
  unsigned short* h1b = (unsigned short*)alloc((size_t)N_NODES * 128 * 2);
  unsigned short* h2b = (unsigned short*)alloc((size_t)N_NODES * 64 * 2);

  hipMemsetAsync(cursor, 0, (size_t)NBUCK * 4, stream);
  hipLaunchKernelGGL(k_prep_route, dim3(96 + ROUTE_BLKS), dim3(256), 0, stream,
                     W1, W2, w1h, w1l, w2h, w2l, src, dst, cursor, routed);
  hipLaunchKernelGGL(k_bsort_gemm128, dim3(NBUCK + GEMM_BLKS), dim3(256), 0,
                     stream, routed, cursor, counts, start, sorted_src, x, w1h,
                     w1l, h1b);
  hipLaunchKernelGGL(k_agg128_gemm64, dim3(M_TILES), dim3(256), 0, stream,
                     (const unsigned*)h1b, counts, start, sorted_src, b1, w2h,
                     w2l, h2b);
  hipLaunchKernelGGL(k_agg64, dim3(M_TILES), dim3(256), 0, stream,
                     (const unsigned*)h2b, counts, start, sorted_src, b2,
                     (float*)d_out);
}